// Round 1
// baseline (387.649 us; speedup 1.0000x reference)
//
#include <hip/hip_runtime.h>
#include <hip/hip_bf16.h>
#include <stdint.h>

typedef __bf16 bf16;
typedef __bf16 bf16x8 __attribute__((ext_vector_type(8)));
typedef __bf16 bf16x4 __attribute__((ext_vector_type(4)));
typedef float f32x4 __attribute__((ext_vector_type(4)));

#define MFMA16(a, b, c) __builtin_amdgcn_mfma_f32_16x16x32_bf16((a), (b), (c), 0, 0, 0)

constexpr int Bc = 2, Sc = 2048, Dc = 1024, Hc = 16, DKc = 64;
constexpr int Mc = Bc * Sc;   // 4096 rows (B*S)
constexpr int MW = Sc / 64;   // 32 mask words per (b,q) row

// ---------------- mask (int32 0/1) -> 64-bit bitmask ----------------
__global__ __launch_bounds__(256) void packmask_kernel(const int* __restrict__ mask,
                                                       unsigned long long* __restrict__ mb,
                                                       int nwords) {
  const int lane = threadIdx.x & 63;
  const int wid = (blockIdx.x * blockDim.x + threadIdx.x) >> 6;
  const int nw = (gridDim.x * blockDim.x) >> 6;
  for (int i = wid; i < nwords; i += nw) {
    int v = mask[(size_t)i * 64 + lane];
    unsigned long long bits = __ballot(v != 0);
    if (lane == 0) mb[i] = bits;
  }
}

// ---------------- GEMM: C[m][n] = sum_k A[m][k] * W[n][k] + bias[n] ----------------
// MODE 0: bf16 row-major [M][N] out.  MODE 1: bf16 Vt[b][h][dk][s] out.  MODE 2: f32 [M][N] out.
// AF32: A is fp32 (convert to bf16 during staging); weights always fp32 converted in staging.
struct Smem {
  bf16 As[128][40];  // row stride 80B: 16B-aligned b128 frag reads, ~2-way banks max
  bf16 Bs[128][40];
};

template <int MODE, bool AF32>
__device__ __forceinline__ void gemm_body(Smem& sm, const void* __restrict__ Aptr,
                                          const float* __restrict__ Bw,
                                          const float* __restrict__ bias,
                                          void* __restrict__ Cout,
                                          int m0, int n0, int Kk, int Nn) {
  const int t = threadIdx.x;
  const int lane = t & 63;
  const int wv = t >> 6;
  const int c = lane & 15, g = lane >> 4;
  const int wr = wv >> 1, wc = wv & 1;
  const f32x4 fz = {0.f, 0.f, 0.f, 0.f};
  f32x4 acc[4][4];
#pragma unroll
  for (int i = 0; i < 4; ++i)
#pragma unroll
    for (int j = 0; j < 4; ++j) acc[i][j] = fz;

  for (int k0 = 0; k0 < Kk; k0 += 32) {
    // ---- stage A tile (128 x 32) ----
    if constexpr (AF32) {
      const float* Af = (const float*)Aptr;
#pragma unroll
      for (int u = 0; u < 4; ++u) {
        int vv = t + u * 256;
        int row = vv >> 3, col = (vv & 7) * 4;
        float4 f = *(const float4*)&Af[(size_t)(m0 + row) * Kk + k0 + col];
        bf16x4 o;
        o[0] = (bf16)f.x; o[1] = (bf16)f.y; o[2] = (bf16)f.z; o[3] = (bf16)f.w;
        *(bf16x4*)&sm.As[row][col] = o;
      }
    } else {
      const bf16* Ab = (const bf16*)Aptr;
#pragma unroll
      for (int u = 0; u < 2; ++u) {
        int vv = t + u * 256;
        int row = vv >> 2, col = (vv & 3) * 8;
        *(bf16x8*)&sm.As[row][col] = *(const bf16x8*)&Ab[(size_t)(m0 + row) * Kk + k0 + col];
      }
    }
    // ---- stage B tile (weights, fp32 -> bf16) ----
#pragma unroll
    for (int u = 0; u < 4; ++u) {
      int vv = t + u * 256;
      int row = vv >> 3, col = (vv & 7) * 4;
      float4 f = *(const float4*)&Bw[(size_t)(n0 + row) * Kk + k0 + col];
      bf16x4 o;
      o[0] = (bf16)f.x; o[1] = (bf16)f.y; o[2] = (bf16)f.z; o[3] = (bf16)f.w;
      *(bf16x4*)&sm.Bs[row][col] = o;
    }
    __syncthreads();

    bf16x8 af[4], bfr[4];
#pragma unroll
    for (int mt = 0; mt < 4; ++mt) af[mt] = *(const bf16x8*)&sm.As[wr * 64 + mt * 16 + c][8 * g];
#pragma unroll
    for (int nt = 0; nt < 4; ++nt) bfr[nt] = *(const bf16x8*)&sm.Bs[wc * 64 + nt * 16 + c][8 * g];
#pragma unroll
    for (int mt = 0; mt < 4; ++mt)
#pragma unroll
      for (int nt = 0; nt < 4; ++nt) acc[mt][nt] = MFMA16(af[mt], bfr[nt], acc[mt][nt]);
    __syncthreads();
  }

  // ---- epilogue: C/D layout (verified): col = lane&15, row = 4*(lane>>4) + reg ----
  const int colb = n0 + wc * 64 + c;
  const int mrowb = m0 + wr * 64 + 4 * g;
#pragma unroll
  for (int mt = 0; mt < 4; ++mt) {
#pragma unroll
    for (int nt = 0; nt < 4; ++nt) {
      const int col = colb + nt * 16;
      const int mrow = mrowb + mt * 16;
      const float bb = bias[col];
      f32x4 a = acc[mt][nt];
      if constexpr (MODE == 0) {
        bf16* out = (bf16*)Cout;
#pragma unroll
        for (int r = 0; r < 4; ++r) out[(size_t)(mrow + r) * Nn + col] = (bf16)(a[r] + bb);
      } else if constexpr (MODE == 2) {
        float* out = (float*)Cout;
#pragma unroll
        for (int r = 0; r < 4; ++r) out[(size_t)(mrow + r) * Nn + col] = a[r] + bb;
      } else {  // MODE 1: Vt[b][h][dk][s], 4 consecutive s per lane -> packed 8B store
        bf16* out = (bf16*)Cout;
        const int batch = mrow >> 11, s = mrow & (Sc - 1);
        const int hh = col >> 6, dd = col & 63;
        bf16x4 pk;
#pragma unroll
        for (int r = 0; r < 4; ++r) pk[r] = (bf16)(a[r] + bb);
        *(bf16x4*)&out[((size_t)((batch * Hc + hh) * DKc + dd)) * Sc + s] = pk;
      }
    }
  }
}

__global__ __launch_bounds__(256) void gemm_qkv_kernel(
    const float* __restrict__ q, const float* __restrict__ k, const float* __restrict__ v,
    const float* __restrict__ Wq, const float* __restrict__ Wk, const float* __restrict__ Wv,
    const float* __restrict__ bq, const float* __restrict__ bk, const float* __restrict__ bv,
    bf16* __restrict__ qh, bf16* __restrict__ kh, bf16* __restrict__ vt) {
  __shared__ Smem sm;
  const int m0 = blockIdx.y * 128, n0 = blockIdx.x * 128;
  if (blockIdx.z == 0)      gemm_body<0, true>(sm, q, Wq, bq, qh, m0, n0, Dc, Dc);
  else if (blockIdx.z == 1) gemm_body<0, true>(sm, k, Wk, bk, kh, m0, n0, Dc, Dc);
  else                      gemm_body<1, true>(sm, v, Wv, bv, vt, m0, n0, Dc, Dc);
}

__global__ __launch_bounds__(256) void gemm_o_kernel(const bf16* __restrict__ ctxp,
                                                     const float* __restrict__ Wo,
                                                     const float* __restrict__ bo,
                                                     float* __restrict__ outp) {
  __shared__ Smem sm;
  gemm_body<2, false>(sm, ctxp, Wo, bo, outp, blockIdx.y * 128, blockIdx.x * 128, Dc, Dc);
}

// ---------------- flash attention: 4 independent waves/block, 16 q-rows/wave ----------------
__global__ __launch_bounds__(256) void attn_kernel(const bf16* __restrict__ qh,
                                                   const bf16* __restrict__ kh,
                                                   const bf16* __restrict__ vt,
                                                   const unsigned long long* __restrict__ mb,
                                                   bf16* __restrict__ ctx) {
  __shared__ bf16 Plds[4][16][72];  // per-wave P tile, row stride 144B (16B aligned)
  const int lane = threadIdx.x & 63;
  const int wv = threadIdx.x >> 6;
  const int c = lane & 15, g = lane >> 4;
  const int qt = blockIdx.x, h = blockIdx.y, b = blockIdx.z;
  const int qbase = qt * 64 + wv * 16;

  const bf16* Qp = qh + (size_t)(b * Sc + qbase) * Dc + h * DKc;
  const bf16* Kp = kh + (size_t)(b * Sc) * Dc + h * DKc;
  const bf16* Vp = vt + (size_t)((b * Hc + h) * DKc) * Sc;
  const unsigned long long* mbp = mb + (size_t)(b * Sc + qbase) * MW;

  bf16x8 aq[2];  // Q fragments hoisted (A: row=lane&15, k=8*(lane>>4)+i over dk=64)
#pragma unroll
  for (int ks = 0; ks < 2; ++ks) aq[ks] = *(const bf16x8*)&Qp[(size_t)c * Dc + 32 * ks + 8 * g];

  const f32x4 fz = {0.f, 0.f, 0.f, 0.f};
  f32x4 oacc[4];  // ctx[q=4g+r][d=c+16*nb]
#pragma unroll
  for (int nb = 0; nb < 4; ++nb) oacc[nb] = fz;
  float mrun[4], lrun[4];
#pragma unroll
  for (int r = 0; r < 4; ++r) { mrun[r] = -__builtin_inff(); lrun[r] = 0.f; }

  for (int kt = 0; kt < Sc; kt += 64) {
    unsigned long long w[4];
#pragma unroll
    for (int r = 0; r < 4; ++r) w[r] = mbp[(size_t)(4 * g + r) * MW + (kt >> 6)];

    // S tile [16q x 64k]: 4 n-tiles x 2 k-steps
    f32x4 sacc[4];
#pragma unroll
    for (int tt = 0; tt < 4; ++tt) sacc[tt] = fz;
#pragma unroll
    for (int ks = 0; ks < 2; ++ks)
#pragma unroll
      for (int tt = 0; tt < 4; ++tt) {
        bf16x8 bk = *(const bf16x8*)&Kp[(size_t)(kt + tt * 16 + c) * Dc + 32 * ks + 8 * g];
        sacc[tt] = MFMA16(aq[ks], bk, sacc[tt]);
      }

    // scale + mask (lane holds S[q=4g+r][k=16*tt+c])
    float sv[4][4];
#pragma unroll
    for (int tt = 0; tt < 4; ++tt)
#pragma unroll
      for (int r = 0; r < 4; ++r) {
        float s = sacc[tt][r] * 0.125f;
        sv[tt][r] = ((w[r] >> (tt * 16 + c)) & 1ULL) ? s : -1e10f;
      }

    // online softmax: row q spread over 16 lanes of group g -> xor-reduce 1,2,4,8
    float al[4];
#pragma unroll
    for (int r = 0; r < 4; ++r) {
      float tm = fmaxf(fmaxf(sv[0][r], sv[1][r]), fmaxf(sv[2][r], sv[3][r]));
#pragma unroll
      for (int d = 1; d < 16; d <<= 1) tm = fmaxf(tm, __shfl_xor(tm, d));
      float mnew = fmaxf(mrun[r], tm);
      al[r] = __expf(mrun[r] - mnew);
      mrun[r] = mnew;
    }
    float ps[4] = {0.f, 0.f, 0.f, 0.f};
#pragma unroll
    for (int tt = 0; tt < 4; ++tt)
#pragma unroll
      for (int r = 0; r < 4; ++r) {
        float p = __expf(sv[tt][r] - mrun[r]);
        ps[r] += p;
        Plds[wv][4 * g + r][tt * 16 + c] = (bf16)p;
      }
#pragma unroll
    for (int r = 0; r < 4; ++r) {
#pragma unroll
      for (int d = 1; d < 16; d <<= 1) ps[r] += __shfl_xor(ps[r], d);
      lrun[r] = lrun[r] * al[r] + ps[r];
    }
#pragma unroll
    for (int nb = 0; nb < 4; ++nb)
#pragma unroll
      for (int r = 0; r < 4; ++r) oacc[nb][r] *= al[r];

    // ensure P writes are committed before same-wave re-read
    asm volatile("s_waitcnt lgkmcnt(0)" ::: "memory");

    // PV: ctx += P[16x64] * V[64k x 64d]; B-frags from row-contiguous Vt
#pragma unroll
    for (int ks = 0; ks < 2; ++ks) {
      bf16x8 pa = *(const bf16x8*)&Plds[wv][c][32 * ks + 8 * g];
#pragma unroll
      for (int nb = 0; nb < 4; ++nb) {
        bf16x8 bv = *(const bf16x8*)&Vp[(size_t)(c + 16 * nb) * Sc + kt + 32 * ks + 8 * g];
        oacc[nb] = MFMA16(pa, bv, oacc[nb]);
      }
    }
  }

  // normalize + write ctx (bf16 [B*S][D])
#pragma unroll
  for (int nb = 0; nb < 4; ++nb) {
#pragma unroll
    for (int r = 0; r < 4; ++r) {
      float val = oacc[nb][r] / lrun[r];
      ctx[(size_t)(b * Sc + qbase + 4 * g + r) * Dc + h * DKc + 16 * nb + c] = (bf16)val;
    }
  }
}

extern "C" void kernel_launch(void* const* d_in, const int* in_sizes, int n_in,
                              void* d_out, int out_size, void* d_ws, size_t ws_size,
                              hipStream_t stream) {
  (void)in_sizes; (void)n_in; (void)out_size; (void)ws_size;
  const float* q  = (const float*)d_in[0];
  const float* k  = (const float*)d_in[1];
  const float* v  = (const float*)d_in[2];
  const float* Wq = (const float*)d_in[3];
  const float* bq = (const float*)d_in[4];
  const float* Wk = (const float*)d_in[5];
  const float* bk = (const float*)d_in[6];
  const float* Wv = (const float*)d_in[7];
  const float* bv = (const float*)d_in[8];
  const float* Wo = (const float*)d_in[9];
  const float* bo = (const float*)d_in[10];
  const int* mask = (const int*)d_in[11];

  char* ws = (char*)d_ws;
  size_t off = 0;
  auto take = [&](size_t bytes) -> void* {
    void* p = ws + off;
    off += (bytes + 255) & ~(size_t)255;
    return p;
  };
  bf16* qh  = (bf16*)take((size_t)Mc * Dc * 2);                 // Q proj [B*S][D]
  bf16* kh  = (bf16*)take((size_t)Mc * Dc * 2);                 // K proj [B*S][D]
  bf16* vt  = (bf16*)take((size_t)Mc * Dc * 2);                 // V proj transposed [B][H][dk][S]
  bf16* ctx = (bf16*)take((size_t)Mc * Dc * 2);                 // attention output [B*S][D]
  unsigned long long* mbits = (unsigned long long*)take((size_t)Bc * Sc * MW * 8);

  packmask_kernel<<<512, 256, 0, stream>>>(mask, mbits, Bc * Sc * Sc / 64);
  gemm_qkv_kernel<<<dim3(Dc / 128, Mc / 128, 3), 256, 0, stream>>>(q, k, v, Wq, Wk, Wv,
                                                                   bq, bk, bv, qh, kh, vt);
  attn_kernel<<<dim3(Sc / 64, Hc, Bc), 256, 0, stream>>>(qh, kh, vt, mbits, ctx);
  gemm_o_kernel<<<dim3(Dc / 128, Mc / 128), 256, 0, stream>>>(ctx, Wo, bo, (float*)d_out);
}

// Round 2
// 271.958 us; speedup vs baseline: 1.4254x; 1.4254x over previous
//
#include <hip/hip_runtime.h>
#include <hip/hip_bf16.h>
#include <stdint.h>

typedef __bf16 bf16;
typedef __bf16 bf16x2 __attribute__((ext_vector_type(2)));
typedef __bf16 bf16x4 __attribute__((ext_vector_type(4)));
typedef __bf16 bf16x8 __attribute__((ext_vector_type(8)));
typedef float f32x4 __attribute__((ext_vector_type(4)));
typedef float f32x16 __attribute__((ext_vector_type(16)));
typedef unsigned int u32;
typedef u32 u32x4 __attribute__((ext_vector_type(4)));
typedef unsigned long long u64;

#define MFMA16(a, b, c) __builtin_amdgcn_mfma_f32_16x16x32_bf16((a), (b), (c), 0, 0, 0)
#define MFMA32(a, b, c) __builtin_amdgcn_mfma_f32_32x32x16_bf16((a), (b), (c), 0, 0, 0)

constexpr int Bc = 2, Sc = 2048, Dc = 1024, Hc = 16, DKc = 64;
constexpr int Mc = Bc * Sc;   // 4096 rows (B*S)
constexpr int MW = Sc / 64;   // 32 mask words per (b,q) row

__device__ __forceinline__ u32 pk2(float a, float b) {
  bf16x2 t; t[0] = (bf16)a; t[1] = (bf16)b;
  return __builtin_bit_cast(u32, t);
}

// ---------------- mask (int32 0/1) -> 64-bit bitmask ----------------
__global__ __launch_bounds__(256) void packmask_kernel(const int* __restrict__ mask,
                                                       u64* __restrict__ mb, int nwords) {
  const int lane = threadIdx.x & 63;
  const int wid = (blockIdx.x * blockDim.x + threadIdx.x) >> 6;
  const int nw = (gridDim.x * blockDim.x) >> 6;
  for (int i = wid; i < nwords; i += nw) {
    int v = mask[(size_t)i * 64 + lane];
    u64 bits = __ballot(v != 0);
    if (lane == 0) mb[i] = bits;
  }
}

// ---------------- GEMM: C[m][n] = sum_k A[m][k] * (scale*W[n][k]) + scale*bias[n] ----------------
struct Smem {
  bf16 As[128][40];
  bf16 Bs[128][40];
};

template <int MODE, bool AF32>
__device__ __forceinline__ void gemm_body(Smem& sm, const void* __restrict__ Aptr,
                                          const float* __restrict__ Bw,
                                          const float* __restrict__ bias,
                                          void* __restrict__ Cout,
                                          int m0, int n0, int Kk, int Nn, float scale) {
  const int t = threadIdx.x;
  const int lane = t & 63;
  const int wv = t >> 6;
  const int c = lane & 15, g = lane >> 4;
  const int wr = wv >> 1, wc = wv & 1;
  const f32x4 fz = {0.f, 0.f, 0.f, 0.f};
  f32x4 acc[4][4];
#pragma unroll
  for (int i = 0; i < 4; ++i)
#pragma unroll
    for (int j = 0; j < 4; ++j) acc[i][j] = fz;

  for (int k0 = 0; k0 < Kk; k0 += 32) {
    if constexpr (AF32) {
      const float* Af = (const float*)Aptr;
#pragma unroll
      for (int u = 0; u < 4; ++u) {
        int vv = t + u * 256;
        int row = vv >> 3, col = (vv & 7) * 4;
        float4 f = *(const float4*)&Af[(size_t)(m0 + row) * Kk + k0 + col];
        bf16x4 o;
        o[0] = (bf16)f.x; o[1] = (bf16)f.y; o[2] = (bf16)f.z; o[3] = (bf16)f.w;
        *(bf16x4*)&sm.As[row][col] = o;
      }
    } else {
      const bf16* Ab = (const bf16*)Aptr;
#pragma unroll
      for (int u = 0; u < 2; ++u) {
        int vv = t + u * 256;
        int row = vv >> 2, col = (vv & 3) * 8;
        *(bf16x8*)&sm.As[row][col] = *(const bf16x8*)&Ab[(size_t)(m0 + row) * Kk + k0 + col];
      }
    }
#pragma unroll
    for (int u = 0; u < 4; ++u) {
      int vv = t + u * 256;
      int row = vv >> 3, col = (vv & 7) * 4;
      float4 f = *(const float4*)&Bw[(size_t)(n0 + row) * Kk + k0 + col];
      bf16x4 o;
      o[0] = (bf16)(f.x * scale); o[1] = (bf16)(f.y * scale);
      o[2] = (bf16)(f.z * scale); o[3] = (bf16)(f.w * scale);
      *(bf16x4*)&sm.Bs[row][col] = o;
    }
    __syncthreads();

    bf16x8 af[4], bfr[4];
#pragma unroll
    for (int mt = 0; mt < 4; ++mt) af[mt] = *(const bf16x8*)&sm.As[wr * 64 + mt * 16 + c][8 * g];
#pragma unroll
    for (int nt = 0; nt < 4; ++nt) bfr[nt] = *(const bf16x8*)&sm.Bs[wc * 64 + nt * 16 + c][8 * g];
#pragma unroll
    for (int mt = 0; mt < 4; ++mt)
#pragma unroll
      for (int nt = 0; nt < 4; ++nt) acc[mt][nt] = MFMA16(af[mt], bfr[nt], acc[mt][nt]);
    __syncthreads();
  }

  const int colb = n0 + wc * 64 + c;
  const int mrowb = m0 + wr * 64 + 4 * g;
#pragma unroll
  for (int mt = 0; mt < 4; ++mt) {
#pragma unroll
    for (int nt = 0; nt < 4; ++nt) {
      const int col = colb + nt * 16;
      const int mrow = mrowb + mt * 16;
      const float bb = bias[col] * scale;
      f32x4 a = acc[mt][nt];
      if constexpr (MODE == 0) {
        bf16* out = (bf16*)Cout;
#pragma unroll
        for (int r = 0; r < 4; ++r) out[(size_t)(mrow + r) * Nn + col] = (bf16)(a[r] + bb);
      } else if constexpr (MODE == 2) {
        float* out = (float*)Cout;
#pragma unroll
        for (int r = 0; r < 4; ++r) out[(size_t)(mrow + r) * Nn + col] = a[r] + bb;
      } else {  // MODE 1: Vt[b][h][dk][s]
        bf16* out = (bf16*)Cout;
        const int batch = mrow >> 11, s = mrow & (Sc - 1);
        const int hh = col >> 6, dd = col & 63;
        bf16x4 pkv;
#pragma unroll
        for (int r = 0; r < 4; ++r) pkv[r] = (bf16)(a[r] + bb);
        *(bf16x4*)&out[((size_t)((batch * Hc + hh) * DKc + dd)) * Sc + s] = pkv;
      }
    }
  }
}

__global__ __launch_bounds__(256) void gemm_qkv_kernel(
    const float* __restrict__ q, const float* __restrict__ k, const float* __restrict__ v,
    const float* __restrict__ Wq, const float* __restrict__ Wk, const float* __restrict__ Wv,
    const float* __restrict__ bq, const float* __restrict__ bk, const float* __restrict__ bv,
    bf16* __restrict__ qh, bf16* __restrict__ kh, bf16* __restrict__ vt) {
  __shared__ Smem sm;
  const int m0 = blockIdx.y * 128, n0 = blockIdx.x * 128;
  // 1/sqrt(dk)=0.125 folded into the Q projection (exact in bf16: exponent shift)
  if (blockIdx.z == 0)      gemm_body<0, true>(sm, q, Wq, bq, qh, m0, n0, Dc, Dc, 0.125f);
  else if (blockIdx.z == 1) gemm_body<0, true>(sm, k, Wk, bk, kh, m0, n0, Dc, Dc, 1.0f);
  else                      gemm_body<1, true>(sm, v, Wv, bv, vt, m0, n0, Dc, Dc, 1.0f);
}

__global__ __launch_bounds__(256) void gemm_o_kernel(const bf16* __restrict__ ctxp,
                                                     const float* __restrict__ Wo,
                                                     const float* __restrict__ bo,
                                                     float* __restrict__ outp) {
  __shared__ Smem sm;
  gemm_body<2, false>(sm, ctxp, Wo, bo, outp, blockIdx.y * 128, blockIdx.x * 128, Dc, Dc, 1.0f);
}

// ---------------- flash attention, swapped operands, in-register softmax ----------------
// Per wave: 32 q-rows. S^T = mfma(K, Q): C col = lane&31 = q, row = (r&3)+8*(r>>2)+4*hi = k.
// PV swapped too: ctx^T = mfma(V^T, P^T): C col = q (stats stay lane-local), row = d.
// No LDS, no barriers: P is repacked to B-fragments in-register via one xor-32 exchange.
__global__ __launch_bounds__(256) void attn_kernel(const bf16* __restrict__ qh,
                                                   const bf16* __restrict__ kh,
                                                   const bf16* __restrict__ vt,
                                                   const u64* __restrict__ mb,
                                                   bf16* __restrict__ ctx) {
  const int lane = threadIdx.x & 63;
  const int wv = threadIdx.x >> 6;
  const int ql = lane & 31;
  const int hi = lane >> 5;
  const int h = blockIdx.y, b = blockIdx.z;
  const int q0 = blockIdx.x * 128 + wv * 32;
  const int qrow = q0 + ql;

  const bf16* Qp = qh + (size_t)(b * Sc + qrow) * Dc + h * DKc;
  const bf16* Kp = kh + (size_t)b * Sc * Dc + h * DKc;
  const bf16* Vp = vt + (size_t)(b * Hc + h) * DKc * Sc;
  const u64* mbp = mb + (size_t)(b * Sc + qrow) * MW;

  bf16x8 qf[4];  // Q B-frags: lane holds Q[q=ql][dk=16ka+8hi+j] (scale pre-folded)
#pragma unroll
  for (int ka = 0; ka < 4; ++ka) qf[ka] = *(const bf16x8*)&Qp[16 * ka + 8 * hi];

  f32x16 oacc[2];
#pragma unroll
  for (int dt = 0; dt < 2; ++dt)
#pragma unroll
    for (int r = 0; r < 16; ++r) oacc[dt][r] = 0.f;
  float mrun = -1e30f, lrun = 0.f;

  for (int kt = 0; kt < Sc; kt += 64) {
    const u64 w = mbp[kt >> 6];

    // S^T tiles: st[t] covers k in [kt+32t, kt+32t+32), all 32 q
    f32x16 st[2];
#pragma unroll
    for (int t = 0; t < 2; ++t) {
#pragma unroll
      for (int r = 0; r < 16; ++r) st[t][r] = 0.f;
      const bf16* kb = &Kp[(size_t)(kt + 32 * t + ql) * Dc + 8 * hi];
#pragma unroll
      for (int ka = 0; ka < 4; ++ka) {
        bf16x8 kf = *(const bf16x8*)&kb[16 * ka];
        st[t] = MFMA32(kf, qf[ka], st[t]);
      }
    }

    // mask + tile max (value (t,r) is k = 32t + (r&3)+8*(r>>2)+4hi for q=ql)
    const u32 wt0 = (u32)(w >> (4 * hi));
    const u32 wt1 = (u32)(w >> (32 + 4 * hi));
    float mx[4] = {-1e30f, -1e30f, -1e30f, -1e30f};
#pragma unroll
    for (int t = 0; t < 2; ++t) {
      const u32 wt = t ? wt1 : wt0;
#pragma unroll
      for (int r = 0; r < 16; ++r) {
        const int bit = (r & 3) + 8 * (r >> 2);
        float s = ((wt >> bit) & 1u) ? (float)st[t][r] : -1e10f;
        st[t][r] = s;
        mx[r & 3] = fmaxf(mx[r & 3], s);
      }
    }
    float tm = fmaxf(fmaxf(mx[0], mx[1]), fmaxf(mx[2], mx[3]));
    tm = fmaxf(tm, __shfl_xor(tm, 32));
    const float mnew = fmaxf(mrun, tm);
    const float alpha = __expf(mrun - mnew);
    mrun = mnew;

    // p = exp(s - m), row sum
    float sm4[4] = {0.f, 0.f, 0.f, 0.f};
#pragma unroll
    for (int t = 0; t < 2; ++t)
#pragma unroll
      for (int r = 0; r < 16; ++r) {
        float p = __expf((float)st[t][r] - mnew);
        sm4[r & 3] += p;
        st[t][r] = p;
      }
    float ls = (sm4[0] + sm4[1]) + (sm4[2] + sm4[3]);
    ls += __shfl_xor(ls, 32);
    lrun = lrun * alpha + ls;
#pragma unroll
    for (int dt = 0; dt < 2; ++dt)
#pragma unroll
      for (int r = 0; r < 16; ++r) oacc[dt][r] *= alpha;

    // pack P rows to bf16 and assemble PV B-frags: pb[ks] = P[q=ql][k=16ks+8hi+j]
    u32x4 pb[4];
#pragma unroll
    for (int t = 0; t < 2; ++t) {
      u32 G[4][2];
#pragma unroll
      for (int i = 0; i < 4; ++i) {  // G[i]: k = 32t + 8i + 4hi + {0..3}
        G[i][0] = pk2((float)st[t][4 * i + 0], (float)st[t][4 * i + 1]);
        G[i][1] = pk2((float)st[t][4 * i + 2], (float)st[t][4 * i + 3]);
      }
#pragma unroll
      for (int e = 0; e < 2; ++e) {
        const u32 xlo = hi ? G[2 * e][0] : G[2 * e + 1][0];
        const u32 xhi = hi ? G[2 * e][1] : G[2 * e + 1][1];
        const u32 rlo = __shfl_xor(xlo, 32);
        const u32 rhi = __shfl_xor(xhi, 32);
        const int ks = 2 * t + e;
        if (hi) { pb[ks][0] = rlo; pb[ks][1] = rhi; pb[ks][2] = G[2 * e + 1][0]; pb[ks][3] = G[2 * e + 1][1]; }
        else    { pb[ks][0] = G[2 * e][0]; pb[ks][1] = G[2 * e][1]; pb[ks][2] = rlo; pb[ks][3] = rhi; }
      }
    }

    // PV: ctx^T[d][q] += V^T[d][k] P^T[k][q]
#pragma unroll
    for (int dt = 0; dt < 2; ++dt) {
      const bf16* vb = &Vp[(size_t)(32 * dt + ql) * Sc + kt + 8 * hi];
#pragma unroll
      for (int ks = 0; ks < 4; ++ks) {
        bf16x8 vf = *(const bf16x8*)&vb[16 * ks];
        oacc[dt] = MFMA32(vf, __builtin_bit_cast(bf16x8, pb[ks]), oacc[dt]);
      }
    }
  }

  // normalize + write ctx[q][d] (lane ql owns q, regs own d = 32dt+8i+4hi+rr)
  const float rinv = 1.f / lrun;
  bf16* cp = ctx + (size_t)(b * Sc + qrow) * Dc + h * DKc;
#pragma unroll
  for (int dt = 0; dt < 2; ++dt)
#pragma unroll
    for (int i = 0; i < 4; ++i) {
      bf16x4 o4;
#pragma unroll
      for (int rr = 0; rr < 4; ++rr) o4[rr] = (bf16)(oacc[dt][4 * i + rr] * rinv);
      *(bf16x4*)&cp[32 * dt + 8 * i + 4 * hi] = o4;
    }
}

extern "C" void kernel_launch(void* const* d_in, const int* in_sizes, int n_in,
                              void* d_out, int out_size, void* d_ws, size_t ws_size,
                              hipStream_t stream) {
  (void)in_sizes; (void)n_in; (void)out_size; (void)ws_size;
  const float* q  = (const float*)d_in[0];
  const float* k  = (const float*)d_in[1];
  const float* v  = (const float*)d_in[2];
  const float* Wq = (const float*)d_in[3];
  const float* bq = (const float*)d_in[4];
  const float* Wk = (const float*)d_in[5];
  const float* bk = (const float*)d_in[6];
  const float* Wv = (const float*)d_in[7];
  const float* bv = (const float*)d_in[8];
  const float* Wo = (const float*)d_in[9];
  const float* bo = (const float*)d_in[10];
  const int* mask = (const int*)d_in[11];

  char* ws = (char*)d_ws;
  size_t off = 0;
  auto take = [&](size_t bytes) -> void* {
    void* p = ws + off;
    off += (bytes + 255) & ~(size_t)255;
    return p;
  };
  bf16* qh  = (bf16*)take((size_t)Mc * Dc * 2);
  bf16* kh  = (bf16*)take((size_t)Mc * Dc * 2);
  bf16* vt  = (bf16*)take((size_t)Mc * Dc * 2);
  bf16* ctx = (bf16*)take((size_t)Mc * Dc * 2);
  u64* mbits = (u64*)take((size_t)Bc * Sc * MW * 8);

  packmask_kernel<<<512, 256, 0, stream>>>(mask, mbits, Bc * Sc * Sc / 64);
  gemm_qkv_kernel<<<dim3(Dc / 128, Mc / 128, 3), 256, 0, stream>>>(q, k, v, Wq, Wk, Wv,
                                                                   bq, bk, bv, qh, kh, vt);
  attn_kernel<<<dim3(Sc / 128, Hc, Bc), 256, 0, stream>>>(qh, kh, vt, mbits, ctx);
  gemm_o_kernel<<<dim3(Dc / 128, Mc / 128), 256, 0, stream>>>(ctx, Wo, bo, (float*)d_out);
}

// Round 3
// 216.648 us; speedup vs baseline: 1.7893x; 1.2553x over previous
//
#include <hip/hip_runtime.h>
#include <hip/hip_bf16.h>
#include <stdint.h>

typedef __bf16 bf16;
typedef __bf16 bf16x2 __attribute__((ext_vector_type(2)));
typedef __bf16 bf16x4 __attribute__((ext_vector_type(4)));
typedef __bf16 bf16x8 __attribute__((ext_vector_type(8)));
typedef float f32x4 __attribute__((ext_vector_type(4)));
typedef float f32x16 __attribute__((ext_vector_type(16)));
typedef unsigned int u32;
typedef u32 u32x4 __attribute__((ext_vector_type(4)));
typedef unsigned long long u64;

#define MFMA16(a, b, c) __builtin_amdgcn_mfma_f32_16x16x32_bf16((a), (b), (c), 0, 0, 0)
#define MFMA32(a, b, c) __builtin_amdgcn_mfma_f32_32x32x16_bf16((a), (b), (c), 0, 0, 0)

constexpr int Bc = 2, Sc = 2048, Dc = 1024, Hc = 16, DKc = 64;
constexpr int Mc = Bc * Sc;
constexpr int MW = Sc / 64;
// 1/sqrt(dk) * log2(e): scores produced directly in log2 domain (exp -> v_exp_f32, no mul)
#define QSCALE 0.1803368801111731f

__device__ __forceinline__ u32 pk2(float a, float b) {
  bf16x2 t; t[0] = (bf16)a; t[1] = (bf16)b;
  return __builtin_bit_cast(u32, t);
}

// async global->LDS, 16B per lane; lds dest is wave-uniform base (HW adds lane*16)
__device__ __forceinline__ void gl_lds16(const void* g, void* l) {
  __builtin_amdgcn_global_load_lds((const __attribute__((address_space(1))) void*)g,
                                   (__attribute__((address_space(3))) void*)l, 16, 0, 0);
}

// ---------------- weights fp32 -> bf16 (Wq also scaled by QSCALE) ----------------
__global__ __launch_bounds__(256) void convw_kernel(
    const float* __restrict__ wq, const float* __restrict__ wk,
    const float* __restrict__ wv, const float* __restrict__ wo,
    bf16* __restrict__ dq, bf16* __restrict__ dk2, bf16* __restrict__ dv, bf16* __restrict__ dwo) {
  const int a = blockIdx.y;
  const float* src = a == 0 ? wq : a == 1 ? wk : a == 2 ? wv : wo;
  bf16* dst = a == 0 ? dq : a == 1 ? dk2 : a == 2 ? dv : dwo;
  const float sc = a == 0 ? QSCALE : 1.0f;
  const size_t i = ((size_t)blockIdx.x * 256 + threadIdx.x) * 8;  // 1M elems, grid.x=512 exact
  f32x4 x0 = *(const f32x4*)&src[i];
  f32x4 x1 = *(const f32x4*)&src[i + 4];
  bf16x8 o;
#pragma unroll
  for (int j = 0; j < 4; ++j) { o[j] = (bf16)(x0[j] * sc); o[4 + j] = (bf16)(x1[j] * sc); }
  *(bf16x8*)&dst[i] = o;
}

// ---------------- mask (int32 0/1) -> 64-bit bitmask ----------------
__global__ __launch_bounds__(256) void packmask_kernel(const int* __restrict__ mask,
                                                       u64* __restrict__ mb, int nwords) {
  const int lane = threadIdx.x & 63;
  const int wid = (blockIdx.x * blockDim.x + threadIdx.x) >> 6;
  const int nw = (gridDim.x * blockDim.x) >> 6;
  for (int i = wid; i < nwords; i += nw) {
    int v = mask[(size_t)i * 64 + lane];
    u64 bits = __ballot(v != 0);
    if (lane == 0) mb[i] = bits;
  }
}

// ---------------- fused QKV GEMM: m97-style (global_load_lds + XOR swizzle) ----------------
// LDS invariant (both tiles): LDS[row][slot16] = global[row][slot16 ^ (row&7)]
// A fp32 [128][64] (256B rows, 16 slots); B bf16 [128][64] (128B rows, 8 slots).
__global__ __launch_bounds__(256, 2) void gemm_qkv_kernel(
    const float* __restrict__ q, const float* __restrict__ k, const float* __restrict__ v,
    const bf16* __restrict__ wq, const bf16* __restrict__ wk, const bf16* __restrict__ wv,
    const float* __restrict__ bq, const float* __restrict__ bk, const float* __restrict__ bv,
    bf16* __restrict__ qh, bf16* __restrict__ kh, bf16* __restrict__ vt) {
  __shared__ float As[128 * 64];
  __shared__ bf16 Bs[128 * 64];
  // XCD-chunked decode: per XCD: 3 projs x (4 m-panels x 8 n-cols) -> A panel stays in one L2
  const int d = blockIdx.x;
  const int xcd = d & 7, idx = d >> 3;      // idx 0..95
  const int proj = idx >> 5, w = idx & 31;
  const int n0 = (w & 7) * 128;
  const int m0 = (xcd * 4 + (w >> 3)) * 128;
  const float* Af = proj == 0 ? q : proj == 1 ? k : v;
  const bf16* Bw = proj == 0 ? wq : proj == 1 ? wk : wv;
  const float* bias = proj == 0 ? bq : proj == 1 ? bk : bv;

  const int t = threadIdx.x, lane = t & 63, wv4 = t >> 6;
  const int c = lane & 15, g = lane >> 4;
  const int wr = wv4 >> 1, wc = wv4 & 1;

  f32x4 acc[4][4];
#pragma unroll
  for (int i = 0; i < 4; ++i)
#pragma unroll
    for (int j = 0; j < 4; ++j) acc[i][j] = (f32x4){0.f, 0.f, 0.f, 0.f};

  const int arow_l = lane >> 4;   // A: 4 rows/1KB chunk, 16 slots/row
  const int aslot_l = lane & 15;
  const int brow_l = lane >> 3;   // B: 8 rows/1KB chunk, 8 slots/row
  const int bslot_l = (lane & 7) ^ brow_l;  // row&7 == brow_l (chunk*8 = 0 mod 8)

  for (int k0 = 0; k0 < Dc; k0 += 64) {
#pragma unroll
    for (int u = 0; u < 8; ++u) {
      const int ch = wv4 * 8 + u;
      const int row = ch * 4 + arow_l;
      const int slot = aslot_l ^ (row & 7);
      gl_lds16(&Af[(size_t)(m0 + row) * Dc + k0 + slot * 4], &As[ch * 256]);
    }
#pragma unroll
    for (int u = 0; u < 4; ++u) {
      const int ch = wv4 * 4 + u;
      const int row = ch * 8 + brow_l;
      gl_lds16(&Bw[(size_t)(n0 + row) * Dc + k0 + bslot_l * 8], &Bs[ch * 512]);
    }
    __syncthreads();
#pragma unroll
    for (int ks = 0; ks < 2; ++ks) {
      bf16x8 af[4], bfr[4];
#pragma unroll
      for (int mt = 0; mt < 4; ++mt) {
        const int row = wr * 64 + mt * 16 + c;      // row&7 == c&7
        const int s0 = (8 * ks + 2 * g) ^ (c & 7);
        const int s1 = (8 * ks + 2 * g + 1) ^ (c & 7);
        f32x4 lo = *(const f32x4*)&As[row * 64 + s0 * 4];
        f32x4 hi2 = *(const f32x4*)&As[row * 64 + s1 * 4];
#pragma unroll
        for (int j = 0; j < 4; ++j) { af[mt][j] = (bf16)lo[j]; af[mt][4 + j] = (bf16)hi2[j]; }
      }
#pragma unroll
      for (int nt = 0; nt < 4; ++nt) {
        const int row = wc * 64 + nt * 16 + c;
        const int sl = (4 * ks + g) ^ (c & 7);
        bfr[nt] = *(const bf16x8*)&Bs[row * 64 + sl * 8];
      }
#pragma unroll
      for (int mt = 0; mt < 4; ++mt)
#pragma unroll
        for (int nt = 0; nt < 4; ++nt) acc[mt][nt] = MFMA16(af[mt], bfr[nt], acc[mt][nt]);
    }
    __syncthreads();
  }

  const float bsc = proj == 0 ? QSCALE : 1.0f;
  const int colb = n0 + wc * 64 + c;
  const int mrowb = m0 + wr * 64 + 4 * g;
#pragma unroll
  for (int mt = 0; mt < 4; ++mt) {
#pragma unroll
    for (int nt = 0; nt < 4; ++nt) {
      const int col = colb + nt * 16;
      const int mrow = mrowb + mt * 16;
      const float bb = bias[col] * bsc;
      f32x4 a = acc[mt][nt];
      if (proj == 0) {                      // Q: row-major [M][D]
#pragma unroll
        for (int r = 0; r < 4; ++r) qh[(size_t)(mrow + r) * Dc + col] = (bf16)(a[r] + bb);
      } else if (proj == 1) {               // K: per-head [B][H][S][64]
        const int hh = col >> 6, dd = col & 63;
#pragma unroll
        for (int r = 0; r < 4; ++r) {
          const int mr = mrow + r;
          kh[((size_t)((mr >> 11) * Hc + hh) * Sc + (mr & (Sc - 1))) * DKc + dd] = (bf16)(a[r] + bb);
        }
      } else {                              // V: transposed [B][H][64][S]
        const int batch = mrow >> 11, s = mrow & (Sc - 1);
        const int hh = col >> 6, dd = col & 63;
        bf16x4 pkv;
#pragma unroll
        for (int r = 0; r < 4; ++r) pkv[r] = (bf16)(a[r] + bb);
        *(bf16x4*)&vt[((size_t)((batch * Hc + hh) * DKc + dd)) * Sc + s] = pkv;
      }
    }
  }
}

// ---------------- output GEMM: ctx(bf16) @ Wo^T + bo -> f32; BM=128 BN=64 BK=64 ----------------
__global__ __launch_bounds__(256, 2) void gemm_o_kernel(const bf16* __restrict__ ctxp,
                                                        const bf16* __restrict__ wo,
                                                        const float* __restrict__ bo,
                                                        float* __restrict__ outp) {
  __shared__ bf16 As[128 * 64];
  __shared__ bf16 Bs[64 * 64];
  const int d = blockIdx.x;
  const int xcd = d & 7, idx = d >> 3;        // idx 0..63
  const int n0 = (idx & 15) * 64;
  const int m0 = (xcd * 4 + (idx >> 4)) * 128;

  const int t = threadIdx.x, lane = t & 63, wv4 = t >> 6;
  const int c = lane & 15, g = lane >> 4;
  const int brow_l = lane >> 3;
  const int bslot_l = (lane & 7) ^ brow_l;

  f32x4 acc[2][4];
#pragma unroll
  for (int i = 0; i < 2; ++i)
#pragma unroll
    for (int j = 0; j < 4; ++j) acc[i][j] = (f32x4){0.f, 0.f, 0.f, 0.f};

  for (int k0 = 0; k0 < Dc; k0 += 64) {
#pragma unroll
    for (int u = 0; u < 4; ++u) {
      const int ch = wv4 * 4 + u;            // A: 16 chunks
      const int row = ch * 8 + brow_l;
      gl_lds16(&ctxp[(size_t)(m0 + row) * Dc + k0 + bslot_l * 8], &As[ch * 512]);
    }
    {
      const int ch = wv4;                    // B: 8 chunks, 2 per wave
      const int row = ch * 8 + brow_l;
      gl_lds16(&wo[(size_t)(n0 + row) * Dc + k0 + bslot_l * 8], &Bs[ch * 512]);
      const int ch2 = 4 + wv4;
      const int row2 = ch2 * 8 + brow_l;
      gl_lds16(&wo[(size_t)(n0 + row2) * Dc + k0 + bslot_l * 8], &Bs[ch2 * 512]);
    }
    __syncthreads();
#pragma unroll
    for (int ks = 0; ks < 2; ++ks) {
      bf16x8 af[2], bfr[4];
#pragma unroll
      for (int mt = 0; mt < 2; ++mt) {
        const int row = wv4 * 32 + mt * 16 + c;
        const int sl = (4 * ks + g) ^ (c & 7);
        af[mt] = *(const bf16x8*)&As[row * 64 + sl * 8];
      }
#pragma unroll
      for (int nt = 0; nt < 4; ++nt) {
        const int row = nt * 16 + c;
        const int sl = (4 * ks + g) ^ (c & 7);
        bfr[nt] = *(const bf16x8*)&Bs[row * 64 + sl * 8];
      }
#pragma unroll
      for (int mt = 0; mt < 2; ++mt)
#pragma unroll
        for (int nt = 0; nt < 4; ++nt) acc[mt][nt] = MFMA16(af[mt], bfr[nt], acc[mt][nt]);
    }
    __syncthreads();
  }

  const int colb = n0 + c;
  const int mrowb = m0 + wv4 * 32 + 4 * g;
#pragma unroll
  for (int mt = 0; mt < 2; ++mt)
#pragma unroll
    for (int nt = 0; nt < 4; ++nt) {
      const int col = colb + nt * 16;
      const int mrow = mrowb + mt * 16;
      const float bb = bo[col];
      f32x4 a = acc[mt][nt];
#pragma unroll
      for (int r = 0; r < 4; ++r) outp[(size_t)(mrow + r) * Dc + col] = a[r] + bb;
    }
}

// ---------------- flash attention: swapped operands, reg-softmax, K/V reg prefetch ----------------
__global__ __launch_bounds__(256, 2) void attn_kernel(const bf16* __restrict__ qh,
                                                      const bf16* __restrict__ kh,
                                                      const bf16* __restrict__ vt,
                                                      const u64* __restrict__ mb,
                                                      bf16* __restrict__ ctx) {
  const int d = blockIdx.x;
  const int xcd = d & 7, idx = d >> 3;         // 512 blocks: 4 (b,h) per XCD
  const int bh = xcd * 4 + (idx >> 4), qt = idx & 15;
  const int b = bh >> 4, h = bh & 15;
  const int lane = threadIdx.x & 63, wv4 = threadIdx.x >> 6;
  const int ql = lane & 31, hi = lane >> 5;
  const int qrow = qt * 128 + wv4 * 32 + ql;

  const bf16* Qp = qh + (size_t)(b * Sc + qrow) * Dc + h * DKc;
  const bf16* Kp = kh + (size_t)(b * Hc + h) * Sc * DKc;   // per-head contiguous rows
  const bf16* Vp = vt + (size_t)(b * Hc + h) * DKc * Sc;
  const u64* mbp = mb + (size_t)(b * Sc + qrow) * MW;

  bf16x8 qf[4];
#pragma unroll
  for (int ka = 0; ka < 4; ++ka) qf[ka] = *(const bf16x8*)&Qp[16 * ka + 8 * hi];

  bf16x8 kfr[2][4], vfr[2][4];
  auto loadK = [&](int kt) {
#pragma unroll
    for (int tt = 0; tt < 2; ++tt)
#pragma unroll
      for (int ka = 0; ka < 4; ++ka)
        kfr[tt][ka] = *(const bf16x8*)&Kp[(size_t)(kt + 32 * tt + ql) * DKc + 16 * ka + 8 * hi];
  };
  auto loadV = [&](int kt) {
#pragma unroll
    for (int dt = 0; dt < 2; ++dt)
#pragma unroll
      for (int ks = 0; ks < 4; ++ks)
        vfr[dt][ks] = *(const bf16x8*)&Vp[(size_t)(32 * dt + ql) * Sc + kt + 16 * ks + 8 * hi];
  };

  f32x16 st[2], oacc[2];
#pragma unroll
  for (int i = 0; i < 2; ++i)
#pragma unroll
    for (int r = 0; r < 16; ++r) oacc[i][r] = 0.f;
  float mrun = -1e30f, lrun = 0.f;

  // prologue: S(0), prefetch K(1), V(0)
  loadK(0);
#pragma unroll
  for (int tt = 0; tt < 2; ++tt) {
    f32x16 z;
#pragma unroll
    for (int r = 0; r < 16; ++r) z[r] = 0.f;
#pragma unroll
    for (int ka = 0; ka < 4; ++ka) z = MFMA32(kfr[tt][ka], qf[ka], z);
    st[tt] = z;
  }
  loadK(64);
  loadV(0);
  u64 wcur = mbp[0];

  for (int kt = 0; kt < Sc; kt += 64) {
    const bool last = (kt + 64 >= Sc);
    const int wi = (kt >> 6) + 1;
    const u64 wnext = mbp[wi < MW ? wi : MW - 1];

    // ---- masked online softmax on st (log2 domain; defer-max THR=12) ----
    const u32 wt0 = (u32)(wcur >> (4 * hi));
    const u32 wt1 = (u32)(wcur >> (32 + 4 * hi));
    float mx[4] = {-1e30f, -1e30f, -1e30f, -1e30f};
#pragma unroll
    for (int tt = 0; tt < 2; ++tt) {
      const u32 wt = tt ? wt1 : wt0;
#pragma unroll
      for (int r = 0; r < 16; ++r) {
        const int bit = (r & 3) + 8 * (r >> 2);
        float s = ((wt >> bit) & 1u) ? (float)st[tt][r] : -1e10f;
        st[tt][r] = s;
        mx[r & 3] = fmaxf(mx[r & 3], s);
      }
    }
    float tm = fmaxf(fmaxf(mx[0], mx[1]), fmaxf(mx[2], mx[3]));
    tm = fmaxf(tm, __shfl_xor(tm, 32));
    if (!__all(tm <= mrun + 12.0f)) {
      const float mnew = fmaxf(mrun, tm);
      const float alpha = exp2f(mrun - mnew);
      mrun = mnew;
      lrun *= alpha;
#pragma unroll
      for (int dt = 0; dt < 2; ++dt)
#pragma unroll
        for (int r = 0; r < 16; ++r) oacc[dt][r] *= alpha;
    }
    float sm4[4] = {0.f, 0.f, 0.f, 0.f};
#pragma unroll
    for (int tt = 0; tt < 2; ++tt)
#pragma unroll
      for (int r = 0; r < 16; ++r) {
        float p = exp2f((float)st[tt][r] - mrun);
        sm4[r & 3] += p;
        st[tt][r] = p;
      }
    float ls = (sm4[0] + sm4[1]) + (sm4[2] + sm4[3]);
    ls += __shfl_xor(ls, 32);
    lrun += ls;

    // ---- pack P -> PV B-frags (one xor-32 exchange per pair) ----
    u32x4 pb[4];
#pragma unroll
    for (int tt = 0; tt < 2; ++tt) {
      u32 G[4][2];
#pragma unroll
      for (int i = 0; i < 4; ++i) {
        G[i][0] = pk2((float)st[tt][4 * i + 0], (float)st[tt][4 * i + 1]);
        G[i][1] = pk2((float)st[tt][4 * i + 2], (float)st[tt][4 * i + 3]);
      }
#pragma unroll
      for (int e = 0; e < 2; ++e) {
        const u32 xlo = hi ? G[2 * e][0] : G[2 * e + 1][0];
        const u32 xhi = hi ? G[2 * e][1] : G[2 * e + 1][1];
        const u32 rlo = __shfl_xor(xlo, 32);
        const u32 rhi = __shfl_xor(xhi, 32);
        const int ks = 2 * tt + e;
        if (hi) { pb[ks][0] = rlo; pb[ks][1] = rhi; pb[ks][2] = G[2 * e + 1][0]; pb[ks][3] = G[2 * e + 1][1]; }
        else    { pb[ks][0] = G[2 * e][0]; pb[ks][1] = G[2 * e][1]; pb[ks][2] = rlo; pb[ks][3] = rhi; }
      }
    }

    // ---- next-tile QK (independent of softmax; overlaps via scheduler) + K prefetch ----
    if (!last) {
      __builtin_amdgcn_s_setprio(1);
#pragma unroll
      for (int tt = 0; tt < 2; ++tt) {
        f32x16 z;
#pragma unroll
        for (int r = 0; r < 16; ++r) z[r] = 0.f;
#pragma unroll
        for (int ka = 0; ka < 4; ++ka) z = MFMA32(kfr[tt][ka], qf[ka], z);
        st[tt] = z;
      }
      __builtin_amdgcn_s_setprio(0);
      const int ktn = (kt + 128 <= Sc - 64) ? kt + 128 : Sc - 64;
      loadK(ktn);
    }

    // ---- PV ----
    __builtin_amdgcn_s_setprio(1);
#pragma unroll
    for (int dt = 0; dt < 2; ++dt)
#pragma unroll
      for (int ks = 0; ks < 4; ++ks)
        oacc[dt] = MFMA32(vfr[dt][ks], __builtin_bit_cast(bf16x8, pb[ks]), oacc[dt]);
    __builtin_amdgcn_s_setprio(0);
    if (!last) loadV(kt + 64);
    wcur = wnext;
  }

  const float rinv = 1.f / lrun;
  bf16* cp = ctx + (size_t)(b * Sc + qrow) * Dc + h * DKc;
#pragma unroll
  for (int dt = 0; dt < 2; ++dt)
#pragma unroll
    for (int i = 0; i < 4; ++i) {
      bf16x4 o4;
#pragma unroll
      for (int rr = 0; rr < 4; ++rr) o4[rr] = (bf16)(oacc[dt][4 * i + rr] * rinv);
      *(bf16x4*)&cp[32 * dt + 8 * i + 4 * hi] = o4;
    }
}

extern "C" void kernel_launch(void* const* d_in, const int* in_sizes, int n_in,
                              void* d_out, int out_size, void* d_ws, size_t ws_size,
                              hipStream_t stream) {
  (void)in_sizes; (void)n_in; (void)out_size; (void)ws_size;
  const float* q  = (const float*)d_in[0];
  const float* k  = (const float*)d_in[1];
  const float* v  = (const float*)d_in[2];
  const float* Wq = (const float*)d_in[3];
  const float* bq = (const float*)d_in[4];
  const float* Wk = (const float*)d_in[5];
  const float* bk = (const float*)d_in[6];
  const float* Wv = (const float*)d_in[7];
  const float* bv = (const float*)d_in[8];
  const float* Wo = (const float*)d_in[9];
  const float* bo = (const float*)d_in[10];
  const int* mask = (const int*)d_in[11];

  char* ws = (char*)d_ws;
  size_t off = 0;
  auto take = [&](size_t bytes) -> void* {
    void* p = ws + off;
    off += (bytes + 255) & ~(size_t)255;
    return p;
  };
  bf16* qh  = (bf16*)take((size_t)Mc * Dc * 2);     // Q proj [B*S][D]
  bf16* kh  = (bf16*)take((size_t)Mc * Dc * 2);     // K proj per-head [B][H][S][64]
  bf16* vt  = (bf16*)take((size_t)Mc * Dc * 2);     // V proj transposed [B][H][64][S]
  bf16* ctx = (bf16*)take((size_t)Mc * Dc * 2);     // attn out [B*S][D]
  u64* mbits = (u64*)take((size_t)Bc * Sc * MW * 8);
  bf16* wqb = (bf16*)take((size_t)Dc * Dc * 2);
  bf16* wkb = (bf16*)take((size_t)Dc * Dc * 2);
  bf16* wvb = (bf16*)take((size_t)Dc * Dc * 2);
  bf16* wob = (bf16*)take((size_t)Dc * Dc * 2);

  convw_kernel<<<dim3(512, 4), 256, 0, stream>>>(Wq, Wk, Wv, Wo, wqb, wkb, wvb, wob);
  packmask_kernel<<<512, 256, 0, stream>>>(mask, mbits, Bc * Sc * Sc / 64);
  gemm_qkv_kernel<<<768, 256, 0, stream>>>(q, k, v, wqb, wkb, wvb, bq, bk, bv, qh, kh, vt);
  attn_kernel<<<512, 256, 0, stream>>>(qh, kh, vt, mbits, ctx);
  gemm_o_kernel<<<512, 256, 0, stream>>>(ctx, wob, bo, (float*)d_out);
}

// Round 4
// 177.198 us; speedup vs baseline: 2.1877x; 1.2226x over previous
//
#include <hip/hip_runtime.h>
#include <hip/hip_bf16.h>
#include <stdint.h>

typedef __bf16 bf16;
typedef __bf16 bf16x2 __attribute__((ext_vector_type(2)));
typedef __bf16 bf16x4 __attribute__((ext_vector_type(4)));
typedef __bf16 bf16x8 __attribute__((ext_vector_type(8)));
typedef float f32x4 __attribute__((ext_vector_type(4)));
typedef float f32x16 __attribute__((ext_vector_type(16)));
typedef unsigned int u32;
typedef u32 u32x4 __attribute__((ext_vector_type(4)));
typedef unsigned long long u64;

#define MFMA16(a, b, c) __builtin_amdgcn_mfma_f32_16x16x32_bf16((a), (b), (c), 0, 0, 0)
#define MFMA32(a, b, c) __builtin_amdgcn_mfma_f32_32x32x16_bf16((a), (b), (c), 0, 0, 0)

constexpr int Bc = 2, Sc = 2048, Dc = 1024, Hc = 16, DKc = 64;
constexpr int Mc = Bc * Sc;
constexpr int MW = Sc / 64;
// 1/sqrt(dk) * log2(e): scores produced directly in log2 domain
#define QSCALE 0.1803368801111731f

__device__ __forceinline__ u32 pk2(float a, float b) {
  bf16x2 t; t[0] = (bf16)a; t[1] = (bf16)b;
  return __builtin_bit_cast(u32, t);
}

__device__ __forceinline__ void gl_lds16(const void* g, void* l) {
  __builtin_amdgcn_global_load_lds((const __attribute__((address_space(1))) void*)g,
                                   (__attribute__((address_space(3))) void*)l, 16, 0, 0);
}

// ---------------- weights fp32 -> bf16 (Wq also scaled by QSCALE) ----------------
__global__ __launch_bounds__(256) void convw_kernel(
    const float* __restrict__ wq, const float* __restrict__ wk,
    const float* __restrict__ wv, const float* __restrict__ wo,
    bf16* __restrict__ dq, bf16* __restrict__ dk2, bf16* __restrict__ dv, bf16* __restrict__ dwo) {
  const int a = blockIdx.y;
  const float* src = a == 0 ? wq : a == 1 ? wk : a == 2 ? wv : wo;
  bf16* dst = a == 0 ? dq : a == 1 ? dk2 : a == 2 ? dv : dwo;
  const float sc = a == 0 ? QSCALE : 1.0f;
  const size_t i = ((size_t)blockIdx.x * 256 + threadIdx.x) * 8;
  f32x4 x0 = *(const f32x4*)&src[i];
  f32x4 x1 = *(const f32x4*)&src[i + 4];
  bf16x8 o;
#pragma unroll
  for (int j = 0; j < 4; ++j) { o[j] = (bf16)(x0[j] * sc); o[4 + j] = (bf16)(x1[j] * sc); }
  *(bf16x8*)&dst[i] = o;
}

// ---------------- mask (int32 0/1) -> 64-bit bitmask ----------------
__global__ __launch_bounds__(256) void packmask_kernel(const int* __restrict__ mask,
                                                       u64* __restrict__ mb, int nwords) {
  const int lane = threadIdx.x & 63;
  const int wid = (blockIdx.x * blockDim.x + threadIdx.x) >> 6;
  const int nw = (gridDim.x * blockDim.x) >> 6;
  for (int i = wid; i < nwords; i += nw) {
    int v = mask[(size_t)i * 64 + lane];
    u64 bits = __ballot(v != 0);
    if (lane == 0) mb[i] = bits;
  }
}

// ---------------- fused QKV GEMM (unchanged from R3) ----------------
__global__ __launch_bounds__(256, 2) void gemm_qkv_kernel(
    const float* __restrict__ q, const float* __restrict__ k, const float* __restrict__ v,
    const bf16* __restrict__ wq, const bf16* __restrict__ wk, const bf16* __restrict__ wv,
    const float* __restrict__ bq, const float* __restrict__ bk, const float* __restrict__ bv,
    bf16* __restrict__ qh, bf16* __restrict__ kh, bf16* __restrict__ vt) {
  __shared__ float As[128 * 64];
  __shared__ bf16 Bs[128 * 64];
  const int d = blockIdx.x;
  const int xcd = d & 7, idx = d >> 3;
  const int proj = idx >> 5, w = idx & 31;
  const int n0 = (w & 7) * 128;
  const int m0 = (xcd * 4 + (w >> 3)) * 128;
  const float* Af = proj == 0 ? q : proj == 1 ? k : v;
  const bf16* Bw = proj == 0 ? wq : proj == 1 ? wk : wv;
  const float* bias = proj == 0 ? bq : proj == 1 ? bk : bv;

  const int t = threadIdx.x, lane = t & 63, wv4 = t >> 6;
  const int c = lane & 15, g = lane >> 4;
  const int wr = wv4 >> 1, wc = wv4 & 1;

  f32x4 acc[4][4];
#pragma unroll
  for (int i = 0; i < 4; ++i)
#pragma unroll
    for (int j = 0; j < 4; ++j) acc[i][j] = (f32x4){0.f, 0.f, 0.f, 0.f};

  const int arow_l = lane >> 4;
  const int aslot_l = lane & 15;
  const int brow_l = lane >> 3;
  const int bslot_l = (lane & 7) ^ brow_l;

  for (int k0 = 0; k0 < Dc; k0 += 64) {
#pragma unroll
    for (int u = 0; u < 8; ++u) {
      const int ch = wv4 * 8 + u;
      const int row = ch * 4 + arow_l;
      const int slot = aslot_l ^ (row & 7);
      gl_lds16(&Af[(size_t)(m0 + row) * Dc + k0 + slot * 4], &As[ch * 256]);
    }
#pragma unroll
    for (int u = 0; u < 4; ++u) {
      const int ch = wv4 * 4 + u;
      const int row = ch * 8 + brow_l;
      gl_lds16(&Bw[(size_t)(n0 + row) * Dc + k0 + bslot_l * 8], &Bs[ch * 512]);
    }
    __syncthreads();
#pragma unroll
    for (int ks = 0; ks < 2; ++ks) {
      bf16x8 af[4], bfr[4];
#pragma unroll
      for (int mt = 0; mt < 4; ++mt) {
        const int row = wr * 64 + mt * 16 + c;
        const int s0 = (8 * ks + 2 * g) ^ (c & 7);
        const int s1 = (8 * ks + 2 * g + 1) ^ (c & 7);
        f32x4 lo = *(const f32x4*)&As[row * 64 + s0 * 4];
        f32x4 hi2 = *(const f32x4*)&As[row * 64 + s1 * 4];
#pragma unroll
        for (int j = 0; j < 4; ++j) { af[mt][j] = (bf16)lo[j]; af[mt][4 + j] = (bf16)hi2[j]; }
      }
#pragma unroll
      for (int nt = 0; nt < 4; ++nt) {
        const int row = wc * 64 + nt * 16 + c;
        const int sl = (4 * ks + g) ^ (c & 7);
        bfr[nt] = *(const bf16x8*)&Bs[row * 64 + sl * 8];
      }
#pragma unroll
      for (int mt = 0; mt < 4; ++mt)
#pragma unroll
        for (int nt = 0; nt < 4; ++nt) acc[mt][nt] = MFMA16(af[mt], bfr[nt], acc[mt][nt]);
    }
    __syncthreads();
  }

  const float bsc = proj == 0 ? QSCALE : 1.0f;
  const int colb = n0 + wc * 64 + c;
  const int mrowb = m0 + wr * 64 + 4 * g;
#pragma unroll
  for (int mt = 0; mt < 4; ++mt) {
#pragma unroll
    for (int nt = 0; nt < 4; ++nt) {
      const int col = colb + nt * 16;
      const int mrow = mrowb + mt * 16;
      const float bb = bias[col] * bsc;
      f32x4 a = acc[mt][nt];
      if (proj == 0) {
#pragma unroll
        for (int r = 0; r < 4; ++r) qh[(size_t)(mrow + r) * Dc + col] = (bf16)(a[r] + bb);
      } else if (proj == 1) {
        const int hh = col >> 6, dd = col & 63;
#pragma unroll
        for (int r = 0; r < 4; ++r) {
          const int mr = mrow + r;
          kh[((size_t)((mr >> 11) * Hc + hh) * Sc + (mr & (Sc - 1))) * DKc + dd] = (bf16)(a[r] + bb);
        }
      } else {
        const int batch = mrow >> 11, s = mrow & (Sc - 1);
        const int hh = col >> 6, dd = col & 63;
        bf16x4 pkv;
#pragma unroll
        for (int r = 0; r < 4; ++r) pkv[r] = (bf16)(a[r] + bb);
        *(bf16x4*)&vt[((size_t)((batch * Hc + hh) * DKc + dd)) * Sc + s] = pkv;
      }
    }
  }
}

// ---------------- output GEMM (unchanged from R3) ----------------
__global__ __launch_bounds__(256, 2) void gemm_o_kernel(const bf16* __restrict__ ctxp,
                                                        const bf16* __restrict__ wo,
                                                        const float* __restrict__ bo,
                                                        float* __restrict__ outp) {
  __shared__ bf16 As[128 * 64];
  __shared__ bf16 Bs[64 * 64];
  const int d = blockIdx.x;
  const int xcd = d & 7, idx = d >> 3;
  const int n0 = (idx & 15) * 64;
  const int m0 = (xcd * 4 + (idx >> 4)) * 128;

  const int t = threadIdx.x, lane = t & 63, wv4 = t >> 6;
  const int c = lane & 15, g = lane >> 4;
  const int brow_l = lane >> 3;
  const int bslot_l = (lane & 7) ^ brow_l;

  f32x4 acc[2][4];
#pragma unroll
  for (int i = 0; i < 2; ++i)
#pragma unroll
    for (int j = 0; j < 4; ++j) acc[i][j] = (f32x4){0.f, 0.f, 0.f, 0.f};

  for (int k0 = 0; k0 < Dc; k0 += 64) {
#pragma unroll
    for (int u = 0; u < 4; ++u) {
      const int ch = wv4 * 4 + u;
      const int row = ch * 8 + brow_l;
      gl_lds16(&ctxp[(size_t)(m0 + row) * Dc + k0 + bslot_l * 8], &As[ch * 512]);
    }
    {
      const int ch = wv4;
      const int row = ch * 8 + brow_l;
      gl_lds16(&wo[(size_t)(n0 + row) * Dc + k0 + bslot_l * 8], &Bs[ch * 512]);
      const int ch2 = 4 + wv4;
      const int row2 = ch2 * 8 + brow_l;
      gl_lds16(&wo[(size_t)(n0 + row2) * Dc + k0 + bslot_l * 8], &Bs[ch2 * 512]);
    }
    __syncthreads();
#pragma unroll
    for (int ks = 0; ks < 2; ++ks) {
      bf16x8 af[2], bfr[4];
#pragma unroll
      for (int mt = 0; mt < 2; ++mt) {
        const int row = wv4 * 32 + mt * 16 + c;
        const int sl = (4 * ks + g) ^ (c & 7);
        af[mt] = *(const bf16x8*)&As[row * 64 + sl * 8];
      }
#pragma unroll
      for (int nt = 0; nt < 4; ++nt) {
        const int row = nt * 16 + c;
        const int sl = (4 * ks + g) ^ (c & 7);
        bfr[nt] = *(const bf16x8*)&Bs[row * 64 + sl * 8];
      }
#pragma unroll
      for (int mt = 0; mt < 2; ++mt)
#pragma unroll
        for (int nt = 0; nt < 4; ++nt) acc[mt][nt] = MFMA16(af[mt], bfr[nt], acc[mt][nt]);
    }
    __syncthreads();
  }

  const int colb = n0 + c;
  const int mrowb = m0 + wv4 * 32 + 4 * g;
#pragma unroll
  for (int mt = 0; mt < 2; ++mt)
#pragma unroll
    for (int nt = 0; nt < 4; ++nt) {
      const int col = colb + nt * 16;
      const int mrow = mrowb + mt * 16;
      const float bb = bo[col];
      f32x4 a = acc[mt][nt];
#pragma unroll
      for (int r = 0; r < 4; ++r) outp[(size_t)(mrow + r) * Dc + col] = a[r] + bb;
    }
}

// ---------------- flash attention: LDS-staged K/V, split-KV, reg softmax ----------------
// SPLITS=1: 512 blocks, writes ctx directly. SPLITS=2: 1024 blocks, writes (O',m,l) partials.
template <int SPLITS>
__global__ __launch_bounds__(256, 3) void attn_kernel(const bf16* __restrict__ qh,
                                                      const bf16* __restrict__ kh,
                                                      const bf16* __restrict__ vt,
                                                      const u64* __restrict__ mb,
                                                      bf16* __restrict__ ctx,
                                                      float* __restrict__ opart,
                                                      float2* __restrict__ ml) {
  __shared__ bf16 Ks[2][64 * 64];   // [buf][row 64][col 64], 16B slots XOR-swizzled by row&7
  __shared__ bf16 Vs[2][64 * 64];
  const int d = blockIdx.x;
  const int xcd = d & 7, idx = d >> 3;
  int bh, qt, half;
  if constexpr (SPLITS == 2) {
    bh = xcd * 4 + (idx >> 5);
    const int sub = idx & 31;
    qt = sub >> 1; half = sub & 1;
  } else {
    bh = xcd * 4 + (idx >> 4);
    qt = idx & 15; half = 0;
  }
  const int b = bh >> 4, h = bh & 15;
  const int lane = threadIdx.x & 63, wv4 = threadIdx.x >> 6;
  const int ql = lane & 31, hi = lane >> 5;
  const int qrow = qt * 128 + wv4 * 32 + ql;

  const bf16* Qp = qh + (size_t)(b * Sc + qrow) * Dc + h * DKc;
  const bf16* Kp = kh + (size_t)(b * Hc + h) * Sc * DKc;
  const bf16* Vp = vt + (size_t)(b * Hc + h) * DKc * Sc;
  const u64* mbp = mb + (size_t)(b * Sc + qrow) * MW;

  const int k0 = half * (Sc / SPLITS);
  constexpr int NIT = (Sc / SPLITS) / 64;

  // staging: per wave 2 K-chunks + 2 V-chunks of 8 rows x 64 cols (1KB each)
  const int srow = lane >> 3, sslot = lane & 7;
  auto stage = [&](int buf, int kt) {
#pragma unroll
    for (int u = 0; u < 2; ++u) {
      const int rb = wv4 * 16 + u * 8;
      const int r = rb + srow;
      gl_lds16(&Kp[(size_t)(kt + r) * DKc + (size_t)((sslot ^ (r & 7)) * 8)], &Ks[buf][rb * 64]);
    }
#pragma unroll
    for (int u = 0; u < 2; ++u) {
      const int rb = wv4 * 16 + u * 8;
      const int r = rb + srow;
      gl_lds16(&Vp[(size_t)r * Sc + kt + (sslot ^ (r & 7)) * 8], &Vs[buf][rb * 64]);
    }
  };

  bf16x8 qf[4];
#pragma unroll
  for (int ka = 0; ka < 4; ++ka) qf[ka] = *(const bf16x8*)&Qp[16 * ka + 8 * hi];

  f32x16 oacc[2];
#pragma unroll
  for (int i = 0; i < 2; ++i)
#pragma unroll
    for (int r = 0; r < 16; ++r) oacc[i][r] = 0.f;
  float mrun = -1e30f, lrun = 0.f;

  stage(0, k0);

  for (int it = 0; it < NIT; ++it) {
    const int kt = k0 + it * 64;
    const int buf = it & 1;
    const int ktn = (it + 1 < NIT) ? kt + 64 : kt;  // clamp: harmless restage on last iter
    stage(buf ^ 1, ktn);
    asm volatile("s_waitcnt vmcnt(4)" ::: "memory");  // drain prev iter's 4 stages, keep ours in flight
    __builtin_amdgcn_s_barrier();
    __builtin_amdgcn_sched_barrier(0);

    const u64 w = mbp[kt >> 6];

    // ---- QK^T from LDS: st[tt] covers k in [kt+32tt, +32), all 32 q ----
    f32x16 st[2];
#pragma unroll
    for (int tt = 0; tt < 2; ++tt) {
      const int row = 32 * tt + ql;
      const bf16* kbase = &Ks[buf][row * 64];
      f32x16 z;
#pragma unroll
      for (int r = 0; r < 16; ++r) z[r] = 0.f;
      __builtin_amdgcn_s_setprio(1);
#pragma unroll
      for (int ka = 0; ka < 4; ++ka) {
        bf16x8 kf = *(const bf16x8*)&kbase[((2 * ka + hi) ^ (row & 7)) * 8];
        z = MFMA32(kf, qf[ka], z);
      }
      __builtin_amdgcn_s_setprio(0);
      st[tt] = z;
    }

    // ---- masked online softmax (log2 domain; defer-max THR=12) ----
    const u32 wt0 = (u32)(w >> (4 * hi));
    const u32 wt1 = (u32)(w >> (32 + 4 * hi));
    float mx[4] = {-1e30f, -1e30f, -1e30f, -1e30f};
#pragma unroll
    for (int tt = 0; tt < 2; ++tt) {
      const u32 wt = tt ? wt1 : wt0;
#pragma unroll
      for (int r = 0; r < 16; ++r) {
        const int bit = (r & 3) + 8 * (r >> 2);
        float s = ((wt >> bit) & 1u) ? (float)st[tt][r] : -1e10f;
        st[tt][r] = s;
        mx[r & 3] = fmaxf(mx[r & 3], s);
      }
    }
    float tm = fmaxf(fmaxf(mx[0], mx[1]), fmaxf(mx[2], mx[3]));
    tm = fmaxf(tm, __shfl_xor(tm, 32));
    if (!__all(tm <= mrun + 12.0f)) {
      const float mnew = fmaxf(mrun, tm);
      const float alpha = exp2f(mrun - mnew);
      mrun = mnew;
      lrun *= alpha;
#pragma unroll
      for (int dt = 0; dt < 2; ++dt)
#pragma unroll
        for (int r = 0; r < 16; ++r) oacc[dt][r] *= alpha;
    }
    float sm4[4] = {0.f, 0.f, 0.f, 0.f};
#pragma unroll
    for (int tt = 0; tt < 2; ++tt)
#pragma unroll
      for (int r = 0; r < 16; ++r) {
        float p = exp2f((float)st[tt][r] - mrun);
        sm4[r & 3] += p;
        st[tt][r] = p;
      }
    float ls = (sm4[0] + sm4[1]) + (sm4[2] + sm4[3]);
    ls += __shfl_xor(ls, 32);
    lrun += ls;

    // ---- pack P -> PV B-frags ----
    u32x4 pb[4];
#pragma unroll
    for (int tt = 0; tt < 2; ++tt) {
      u32 G[4][2];
#pragma unroll
      for (int i = 0; i < 4; ++i) {
        G[i][0] = pk2((float)st[tt][4 * i + 0], (float)st[tt][4 * i + 1]);
        G[i][1] = pk2((float)st[tt][4 * i + 2], (float)st[tt][4 * i + 3]);
      }
#pragma unroll
      for (int e = 0; e < 2; ++e) {
        const u32 xlo = hi ? G[2 * e][0] : G[2 * e + 1][0];
        const u32 xhi = hi ? G[2 * e][1] : G[2 * e + 1][1];
        const u32 rlo = __shfl_xor(xlo, 32);
        const u32 rhi = __shfl_xor(xhi, 32);
        const int ks = 2 * tt + e;
        if (hi) { pb[ks][0] = rlo; pb[ks][1] = rhi; pb[ks][2] = G[2 * e + 1][0]; pb[ks][3] = G[2 * e + 1][1]; }
        else    { pb[ks][0] = G[2 * e][0]; pb[ks][1] = G[2 * e][1]; pb[ks][2] = rlo; pb[ks][3] = rhi; }
      }
    }

    // ---- PV from LDS ----
#pragma unroll
    for (int dt = 0; dt < 2; ++dt) {
      const int row = 32 * dt + ql;
      const bf16* vbase = &Vs[buf][row * 64];
      __builtin_amdgcn_s_setprio(1);
#pragma unroll
      for (int ks = 0; ks < 4; ++ks) {
        bf16x8 vf = *(const bf16x8*)&vbase[((2 * ks + hi) ^ (row & 7)) * 8];
        oacc[dt] = MFMA32(vf, __builtin_bit_cast(bf16x8, pb[ks]), oacc[dt]);
      }
      __builtin_amdgcn_s_setprio(0);
    }

    __builtin_amdgcn_sched_barrier(0);
    __builtin_amdgcn_s_barrier();  // all waves done reading buf -> next stage may overwrite
  }

  if constexpr (SPLITS == 2) {
    float* opr = opart + ((size_t)(half * 32 + bh) * Sc + qrow) * 64;
#pragma unroll
    for (int dt = 0; dt < 2; ++dt)
#pragma unroll
      for (int i = 0; i < 4; ++i) {
        f32x4 o4;
#pragma unroll
        for (int rr = 0; rr < 4; ++rr) o4[rr] = oacc[dt][4 * i + rr];
        *(f32x4*)&opr[32 * dt + 8 * i + 4 * hi] = o4;
      }
    if (hi == 0) {
      float2 v2; v2.x = mrun; v2.y = lrun;
      ml[(size_t)(half * 32 + bh) * Sc + qrow] = v2;
    }
  } else {
    const float rinv = 1.f / lrun;
    bf16* cp = ctx + (size_t)(b * Sc + qrow) * Dc + h * DKc;
#pragma unroll
    for (int dt = 0; dt < 2; ++dt)
#pragma unroll
      for (int i = 0; i < 4; ++i) {
        bf16x4 o4;
#pragma unroll
        for (int rr = 0; rr < 4; ++rr) o4[rr] = (bf16)(oacc[dt][4 * i + rr] * rinv);
        *(bf16x4*)&cp[32 * dt + 8 * i + 4 * hi] = o4;
      }
  }
}

// ---------------- combine the two KV-splits: exact f32 flash merge ----------------
__global__ __launch_bounds__(256) void combine_kernel(const float* __restrict__ op,
                                                      const float2* __restrict__ ml,
                                                      bf16* __restrict__ ctx) {
  const int wv = threadIdx.x >> 6, lane = threadIdx.x & 63;
  const size_t row = (size_t)blockIdx.x * 4 + wv;      // bh*2048 + q, 0..65535
  const int bh = (int)(row >> 11), q = (int)(row & 2047);
  const int b = bh >> 4, h = bh & 15;
  const float2 ml0 = ml[row], ml1 = ml[65536 + row];
  const float o0 = op[row * 64 + lane];
  const float o1 = op[(size_t)65536 * 64 + row * 64 + lane];
  const float m = fmaxf(ml0.x, ml1.x);
  const float a0 = exp2f(ml0.x - m), a1 = exp2f(ml1.x - m);
  const float l = a0 * ml0.y + a1 * ml1.y;
  const float o = (a0 * o0 + a1 * o1) / l;
  ctx[((size_t)(b * Sc + q)) * Dc + h * DKc + lane] = (bf16)o;
}

extern "C" void kernel_launch(void* const* d_in, const int* in_sizes, int n_in,
                              void* d_out, int out_size, void* d_ws, size_t ws_size,
                              hipStream_t stream) {
  (void)in_sizes; (void)n_in; (void)out_size;
  const float* q  = (const float*)d_in[0];
  const float* k  = (const float*)d_in[1];
  const float* v  = (const float*)d_in[2];
  const float* Wq = (const float*)d_in[3];
  const float* bq = (const float*)d_in[4];
  const float* Wk = (const float*)d_in[5];
  const float* bk = (const float*)d_in[6];
  const float* Wv = (const float*)d_in[7];
  const float* bv = (const float*)d_in[8];
  const float* Wo = (const float*)d_in[9];
  const float* bo = (const float*)d_in[10];
  const int* mask = (const int*)d_in[11];

  char* ws = (char*)d_ws;
  size_t off = 0;
  auto take = [&](size_t bytes) -> void* {
    void* p = ws + off;
    off += (bytes + 255) & ~(size_t)255;
    return p;
  };
  bf16* qh  = (bf16*)take((size_t)Mc * Dc * 2);
  bf16* kh  = (bf16*)take((size_t)Mc * Dc * 2);
  bf16* vt  = (bf16*)take((size_t)Mc * Dc * 2);
  bf16* ctx = (bf16*)take((size_t)Mc * Dc * 2);
  u64* mbits = (u64*)take((size_t)Bc * Sc * MW * 8);
  bf16* wqb = (bf16*)take((size_t)Dc * Dc * 2);
  bf16* wkb = (bf16*)take((size_t)Dc * Dc * 2);
  bf16* wvb = (bf16*)take((size_t)Dc * Dc * 2);
  bf16* wob = (bf16*)take((size_t)Dc * Dc * 2);
  float* opart = (float*)take((size_t)2 * 32 * Sc * 64 * 4);   // [split][bh][q][64] f32
  float2* mlb = (float2*)take((size_t)2 * 32 * Sc * 8);        // [split][bh][q] (m,l)
  const bool split2 = off <= ws_size;

  convw_kernel<<<dim3(512, 4), 256, 0, stream>>>(Wq, Wk, Wv, Wo, wqb, wkb, wvb, wob);
  packmask_kernel<<<512, 256, 0, stream>>>(mask, mbits, Bc * Sc * Sc / 64);
  gemm_qkv_kernel<<<768, 256, 0, stream>>>(q, k, v, wqb, wkb, wvb, bq, bk, bv, qh, kh, vt);
  if (split2) {
    attn_kernel<2><<<1024, 256, 0, stream>>>(qh, kh, vt, mbits, ctx, opart, mlb);
    combine_kernel<<<16384, 256, 0, stream>>>(opart, mlb, ctx);
  } else {
    attn_kernel<1><<<512, 256, 0, stream>>>(qh, kh, vt, mbits, ctx, opart, mlb);
  }
  gemm_o_kernel<<<512, 256, 0, stream>>>(ctx, wob, bo, (float*)d_out);
}

// Round 5
// 175.179 us; speedup vs baseline: 2.2129x; 1.0115x over previous
//
#include <hip/hip_runtime.h>
#include <hip/hip_bf16.h>
#include <stdint.h>

typedef __bf16 bf16;
typedef __bf16 bf16x2 __attribute__((ext_vector_type(2)));
typedef __bf16 bf16x4 __attribute__((ext_vector_type(4)));
typedef __bf16 bf16x8 __attribute__((ext_vector_type(8)));
typedef float f32x4 __attribute__((ext_vector_type(4)));
typedef float f32x16 __attribute__((ext_vector_type(16)));
typedef unsigned int u32;
typedef u32 u32x4 __attribute__((ext_vector_type(4)));
typedef unsigned long long u64;

#define MFMA16(a, b, c) __builtin_amdgcn_mfma_f32_16x16x32_bf16((a), (b), (c), 0, 0, 0)
#define MFMA32(a, b, c) __builtin_amdgcn_mfma_f32_32x32x16_bf16((a), (b), (c), 0, 0, 0)

constexpr int Bc = 2, Sc = 2048, Dc = 1024, Hc = 16, DKc = 64;
constexpr int Mc = Bc * Sc;
constexpr int MW = Sc / 64;
// 1/sqrt(dk) * log2(e): scores produced directly in log2 domain
#define QSCALE 0.1803368801111731f

__device__ __forceinline__ u32 pk2(float a, float b) {
  bf16x2 t; t[0] = (bf16)a; t[1] = (bf16)b;
  return __builtin_bit_cast(u32, t);
}

__device__ __forceinline__ void gl_lds16(const void* g, void* l) {
  __builtin_amdgcn_global_load_lds((const __attribute__((address_space(1))) void*)g,
                                   (__attribute__((address_space(3))) void*)l, 16, 0, 0);
}

// ---------------- weights fp32 -> bf16 (Wq also scaled by QSCALE) ----------------
__global__ __launch_bounds__(256) void convw_kernel(
    const float* __restrict__ wq, const float* __restrict__ wk,
    const float* __restrict__ wv, const float* __restrict__ wo,
    bf16* __restrict__ dq, bf16* __restrict__ dk2, bf16* __restrict__ dv, bf16* __restrict__ dwo) {
  const int a = blockIdx.y;
  const float* src = a == 0 ? wq : a == 1 ? wk : a == 2 ? wv : wo;
  bf16* dst = a == 0 ? dq : a == 1 ? dk2 : a == 2 ? dv : dwo;
  const float sc = a == 0 ? QSCALE : 1.0f;
  const size_t i = ((size_t)blockIdx.x * 256 + threadIdx.x) * 8;
  f32x4 x0 = *(const f32x4*)&src[i];
  f32x4 x1 = *(const f32x4*)&src[i + 4];
  bf16x8 o;
#pragma unroll
  for (int j = 0; j < 4; ++j) { o[j] = (bf16)(x0[j] * sc); o[4 + j] = (bf16)(x1[j] * sc); }
  *(bf16x8*)&dst[i] = o;
}

// ---------------- mask (int32 0/1) -> 64-bit bitmask ----------------
__global__ __launch_bounds__(256) void packmask_kernel(const int* __restrict__ mask,
                                                       u64* __restrict__ mb, int nwords) {
  const int lane = threadIdx.x & 63;
  const int wid = (blockIdx.x * blockDim.x + threadIdx.x) >> 6;
  const int nw = (gridDim.x * blockDim.x) >> 6;
  for (int i = wid; i < nwords; i += nw) {
    int v = mask[(size_t)i * 64 + lane];
    u64 bits = __ballot(v != 0);
    if (lane == 0) mb[i] = bits;
  }
}

// ---------------- fused QKV GEMM (unchanged) ----------------
__global__ __launch_bounds__(256, 2) void gemm_qkv_kernel(
    const float* __restrict__ q, const float* __restrict__ k, const float* __restrict__ v,
    const bf16* __restrict__ wq, const bf16* __restrict__ wk, const bf16* __restrict__ wv,
    const float* __restrict__ bq, const float* __restrict__ bk, const float* __restrict__ bv,
    bf16* __restrict__ qh, bf16* __restrict__ kh, bf16* __restrict__ vt) {
  __shared__ float As[128 * 64];
  __shared__ bf16 Bs[128 * 64];
  const int d = blockIdx.x;
  const int xcd = d & 7, idx = d >> 3;
  const int proj = idx >> 5, w = idx & 31;
  const int n0 = (w & 7) * 128;
  const int m0 = (xcd * 4 + (w >> 3)) * 128;
  const float* Af = proj == 0 ? q : proj == 1 ? k : v;
  const bf16* Bw = proj == 0 ? wq : proj == 1 ? wk : wv;
  const float* bias = proj == 0 ? bq : proj == 1 ? bk : bv;

  const int t = threadIdx.x, lane = t & 63, wv4 = t >> 6;
  const int c = lane & 15, g = lane >> 4;
  const int wr = wv4 >> 1, wc = wv4 & 1;

  f32x4 acc[4][4];
#pragma unroll
  for (int i = 0; i < 4; ++i)
#pragma unroll
    for (int j = 0; j < 4; ++j) acc[i][j] = (f32x4){0.f, 0.f, 0.f, 0.f};

  const int arow_l = lane >> 4;
  const int aslot_l = lane & 15;
  const int brow_l = lane >> 3;
  const int bslot_l = (lane & 7) ^ brow_l;

  for (int k0 = 0; k0 < Dc; k0 += 64) {
#pragma unroll
    for (int u = 0; u < 8; ++u) {
      const int ch = wv4 * 8 + u;
      const int row = ch * 4 + arow_l;
      const int slot = aslot_l ^ (row & 7);
      gl_lds16(&Af[(size_t)(m0 + row) * Dc + k0 + slot * 4], &As[ch * 256]);
    }
#pragma unroll
    for (int u = 0; u < 4; ++u) {
      const int ch = wv4 * 4 + u;
      const int row = ch * 8 + brow_l;
      gl_lds16(&Bw[(size_t)(n0 + row) * Dc + k0 + bslot_l * 8], &Bs[ch * 512]);
    }
    __syncthreads();
#pragma unroll
    for (int ks = 0; ks < 2; ++ks) {
      bf16x8 af[4], bfr[4];
#pragma unroll
      for (int mt = 0; mt < 4; ++mt) {
        const int row = wr * 64 + mt * 16 + c;
        const int s0 = (8 * ks + 2 * g) ^ (c & 7);
        const int s1 = (8 * ks + 2 * g + 1) ^ (c & 7);
        f32x4 lo = *(const f32x4*)&As[row * 64 + s0 * 4];
        f32x4 hi2 = *(const f32x4*)&As[row * 64 + s1 * 4];
#pragma unroll
        for (int j = 0; j < 4; ++j) { af[mt][j] = (bf16)lo[j]; af[mt][4 + j] = (bf16)hi2[j]; }
      }
#pragma unroll
      for (int nt = 0; nt < 4; ++nt) {
        const int row = wc * 64 + nt * 16 + c;
        const int sl = (4 * ks + g) ^ (c & 7);
        bfr[nt] = *(const bf16x8*)&Bs[row * 64 + sl * 8];
      }
#pragma unroll
      for (int mt = 0; mt < 4; ++mt)
#pragma unroll
        for (int nt = 0; nt < 4; ++nt) acc[mt][nt] = MFMA16(af[mt], bfr[nt], acc[mt][nt]);
    }
    __syncthreads();
  }

  const float bsc = proj == 0 ? QSCALE : 1.0f;
  const int colb = n0 + wc * 64 + c;
  const int mrowb = m0 + wr * 64 + 4 * g;
#pragma unroll
  for (int mt = 0; mt < 4; ++mt) {
#pragma unroll
    for (int nt = 0; nt < 4; ++nt) {
      const int col = colb + nt * 16;
      const int mrow = mrowb + mt * 16;
      const float bb = bias[col] * bsc;
      f32x4 a = acc[mt][nt];
      if (proj == 0) {
#pragma unroll
        for (int r = 0; r < 4; ++r) qh[(size_t)(mrow + r) * Dc + col] = (bf16)(a[r] + bb);
      } else if (proj == 1) {
        const int hh = col >> 6, dd = col & 63;
#pragma unroll
        for (int r = 0; r < 4; ++r) {
          const int mr = mrow + r;
          kh[((size_t)((mr >> 11) * Hc + hh) * Sc + (mr & (Sc - 1))) * DKc + dd] = (bf16)(a[r] + bb);
        }
      } else {
        const int batch = mrow >> 11, s = mrow & (Sc - 1);
        const int hh = col >> 6, dd = col & 63;
        bf16x4 pkv;
#pragma unroll
        for (int r = 0; r < 4; ++r) pkv[r] = (bf16)(a[r] + bb);
        *(bf16x4*)&vt[((size_t)((batch * Hc + hh) * DKc + dd)) * Sc + s] = pkv;
      }
    }
  }
}

// ---------------- output GEMM (unchanged) ----------------
__global__ __launch_bounds__(256, 2) void gemm_o_kernel(const bf16* __restrict__ ctxp,
                                                        const bf16* __restrict__ wo,
                                                        const float* __restrict__ bo,
                                                        float* __restrict__ outp) {
  __shared__ bf16 As[128 * 64];
  __shared__ bf16 Bs[64 * 64];
  const int d = blockIdx.x;
  const int xcd = d & 7, idx = d >> 3;
  const int n0 = (idx & 15) * 64;
  const int m0 = (xcd * 4 + (idx >> 4)) * 128;

  const int t = threadIdx.x, lane = t & 63, wv4 = t >> 6;
  const int c = lane & 15, g = lane >> 4;
  const int brow_l = lane >> 3;
  const int bslot_l = (lane & 7) ^ brow_l;

  f32x4 acc[2][4];
#pragma unroll
  for (int i = 0; i < 2; ++i)
#pragma unroll
    for (int j = 0; j < 4; ++j) acc[i][j] = (f32x4){0.f, 0.f, 0.f, 0.f};

  for (int k0 = 0; k0 < Dc; k0 += 64) {
#pragma unroll
    for (int u = 0; u < 4; ++u) {
      const int ch = wv4 * 4 + u;
      const int row = ch * 8 + brow_l;
      gl_lds16(&ctxp[(size_t)(m0 + row) * Dc + k0 + bslot_l * 8], &As[ch * 512]);
    }
    {
      const int ch = wv4;
      const int row = ch * 8 + brow_l;
      gl_lds16(&wo[(size_t)(n0 + row) * Dc + k0 + bslot_l * 8], &Bs[ch * 512]);
      const int ch2 = 4 + wv4;
      const int row2 = ch2 * 8 + brow_l;
      gl_lds16(&wo[(size_t)(n0 + row2) * Dc + k0 + bslot_l * 8], &Bs[ch2 * 512]);
    }
    __syncthreads();
#pragma unroll
    for (int ks = 0; ks < 2; ++ks) {
      bf16x8 af[2], bfr[4];
#pragma unroll
      for (int mt = 0; mt < 2; ++mt) {
        const int row = wv4 * 32 + mt * 16 + c;
        const int sl = (4 * ks + g) ^ (c & 7);
        af[mt] = *(const bf16x8*)&As[row * 64 + sl * 8];
      }
#pragma unroll
      for (int nt = 0; nt < 4; ++nt) {
        const int row = nt * 16 + c;
        const int sl = (4 * ks + g) ^ (c & 7);
        bfr[nt] = *(const bf16x8*)&Bs[row * 64 + sl * 8];
      }
#pragma unroll
      for (int mt = 0; mt < 2; ++mt)
#pragma unroll
        for (int nt = 0; nt < 4; ++nt) acc[mt][nt] = MFMA16(af[mt], bfr[nt], acc[mt][nt]);
    }
    __syncthreads();
  }

  const int colb = n0 + c;
  const int mrowb = m0 + wv4 * 32 + 4 * g;
#pragma unroll
  for (int mt = 0; mt < 2; ++mt)
#pragma unroll
    for (int nt = 0; nt < 4; ++nt) {
      const int col = colb + nt * 16;
      const int mrow = mrowb + mt * 16;
      const float bb = bo[col];
      f32x4 a = acc[mt][nt];
#pragma unroll
      for (int r = 0; r < 4; ++r) outp[(size_t)(mrow + r) * Dc + col] = a[r] + bb;
    }
}

// ---------------- flash attention: fixed-base softmax (no max), l via ones-MFMA ----------------
// Any common scale cancels in sum(p*v)/sum(p), so p = exp2(s) directly: per score only
// {exp, bfe, cmp, cndmask}. Row-sum l computed by 4 extra MFMA32 with A = ones (MFMA pipe idle).
template <int SPLITS>
__global__ __launch_bounds__(256, 3) void attn_kernel(const bf16* __restrict__ qh,
                                                      const bf16* __restrict__ kh,
                                                      const bf16* __restrict__ vt,
                                                      const u64* __restrict__ mb,
                                                      bf16* __restrict__ ctx,
                                                      float* __restrict__ opart,
                                                      float2* __restrict__ ml) {
  __shared__ bf16 Ks[2][64 * 64];   // [buf][row 64][col 64], 16B slots XOR-swizzled by row&7
  __shared__ bf16 Vs[2][64 * 64];
  const int d = blockIdx.x;
  const int xcd = d & 7, idx = d >> 3;
  int bh, qt, half;
  if constexpr (SPLITS == 2) {
    bh = xcd * 4 + (idx >> 5);
    const int sub = idx & 31;
    qt = sub >> 1; half = sub & 1;
  } else {
    bh = xcd * 4 + (idx >> 4);
    qt = idx & 15; half = 0;
  }
  const int b = bh >> 4, h = bh & 15;
  const int lane = threadIdx.x & 63, wv4 = threadIdx.x >> 6;
  const int ql = lane & 31, hi = lane >> 5;
  const int qrow = qt * 128 + wv4 * 32 + ql;

  const bf16* Qp = qh + (size_t)(b * Sc + qrow) * Dc + h * DKc;
  const bf16* Kp = kh + (size_t)(b * Hc + h) * Sc * DKc;
  const bf16* Vp = vt + (size_t)(b * Hc + h) * DKc * Sc;
  const u64* mbp = mb + (size_t)(b * Sc + qrow) * MW;

  const int k0 = half * (Sc / SPLITS);
  constexpr int NIT = (Sc / SPLITS) / 64;

  const int srow = lane >> 3, sslot = lane & 7;
  auto stage = [&](int buf, int kt) {
#pragma unroll
    for (int u = 0; u < 2; ++u) {
      const int rb = wv4 * 16 + u * 8;
      const int r = rb + srow;
      gl_lds16(&Kp[(size_t)(kt + r) * DKc + (size_t)((sslot ^ (r & 7)) * 8)], &Ks[buf][rb * 64]);
    }
#pragma unroll
    for (int u = 0; u < 2; ++u) {
      const int rb = wv4 * 16 + u * 8;
      const int r = rb + srow;
      gl_lds16(&Vp[(size_t)r * Sc + kt + (sslot ^ (r & 7)) * 8], &Vs[buf][rb * 64]);
    }
  };

  bf16x8 qf[4];
#pragma unroll
  for (int ka = 0; ka < 4; ++ka) qf[ka] = *(const bf16x8*)&Qp[16 * ka + 8 * hi];

  bf16x8 ones8;
#pragma unroll
  for (int j = 0; j < 8; ++j) ones8[j] = (bf16)1.0f;

  f32x16 oacc[2], lacc;
#pragma unroll
  for (int i = 0; i < 2; ++i)
#pragma unroll
    for (int r = 0; r < 16; ++r) oacc[i][r] = 0.f;
#pragma unroll
  for (int r = 0; r < 16; ++r) lacc[r] = 0.f;

  stage(0, k0);
  u64 w = mbp[k0 >> 6];  // mask for tile 0, issued before loop

  for (int it = 0; it < NIT; ++it) {
    const int kt = k0 + it * 64;
    const int buf = it & 1;
    const int ktn = (it + 1 < NIT) ? kt + 64 : kt;  // clamp: harmless restage on last iter
    stage(buf ^ 1, ktn);
    // next-tile mask issued AFTER the 4 stage ops -> compiler's wait for it is vmcnt(4),
    // never vmcnt(0): the in-flight prefetch survives.
    const u64 wnext = mbp[ktn >> 6];
    asm volatile("s_waitcnt vmcnt(4)" ::: "memory");  // drain prev iter's stages, keep ours
    __builtin_amdgcn_s_barrier();
    __builtin_amdgcn_sched_barrier(0);

    // ---- QK^T from LDS: st[tt] covers k in [kt+32tt, +32), all 32 q ----
    f32x16 st[2];
#pragma unroll
    for (int tt = 0; tt < 2; ++tt) {
      const int row = 32 * tt + ql;
      const bf16* kbase = &Ks[buf][row * 64];
      f32x16 z;
#pragma unroll
      for (int r = 0; r < 16; ++r) z[r] = 0.f;
      __builtin_amdgcn_s_setprio(1);
#pragma unroll
      for (int ka = 0; ka < 4; ++ka) {
        bf16x8 kf = *(const bf16x8*)&kbase[((2 * ka + hi) ^ (row & 7)) * 8];
        z = MFMA32(kf, qf[ka], z);
      }
      __builtin_amdgcn_s_setprio(0);
      st[tt] = z;
    }

    // ---- fixed-base softmax: p = exp2(s) (scale cancels in o = sum(p*v)/sum(p)) ----
    // value (tt,r) is k = 32tt + (r&3)+8*(r>>2)+4*hi for q = ql
    const u32 wt0 = (u32)(w >> (4 * hi));
    const u32 wt1 = (u32)(w >> (32 + 4 * hi));
#pragma unroll
    for (int tt = 0; tt < 2; ++tt) {
      const u32 wt = tt ? wt1 : wt0;
#pragma unroll
      for (int r = 0; r < 16; ++r) {
        const int bit = (r & 3) + 8 * (r >> 2);
        const float p = exp2f((float)st[tt][r]);
        st[tt][r] = ((wt >> bit) & 1u) ? p : 0.f;
      }
    }

    // ---- pack P -> PV B-frags ----
    u32x4 pb[4];
#pragma unroll
    for (int tt = 0; tt < 2; ++tt) {
      u32 G[4][2];
#pragma unroll
      for (int i = 0; i < 4; ++i) {
        G[i][0] = pk2((float)st[tt][4 * i + 0], (float)st[tt][4 * i + 1]);
        G[i][1] = pk2((float)st[tt][4 * i + 2], (float)st[tt][4 * i + 3]);
      }
#pragma unroll
      for (int e = 0; e < 2; ++e) {
        const u32 xlo = hi ? G[2 * e][0] : G[2 * e + 1][0];
        const u32 xhi = hi ? G[2 * e][1] : G[2 * e + 1][1];
        const u32 rlo = __shfl_xor(xlo, 32);
        const u32 rhi = __shfl_xor(xhi, 32);
        const int ks = 2 * tt + e;
        if (hi) { pb[ks][0] = rlo; pb[ks][1] = rhi; pb[ks][2] = G[2 * e + 1][0]; pb[ks][3] = G[2 * e + 1][1]; }
        else    { pb[ks][0] = G[2 * e][0]; pb[ks][1] = G[2 * e][1]; pb[ks][2] = rlo; pb[ks][3] = rhi; }
      }
    }

    // ---- l += P^T-colsum via ones-MFMA; PV from LDS ----
    __builtin_amdgcn_s_setprio(1);
#pragma unroll
    for (int ks = 0; ks < 4; ++ks)
      lacc = MFMA32(ones8, __builtin_bit_cast(bf16x8, pb[ks]), lacc);
#pragma unroll
    for (int dt = 0; dt < 2; ++dt) {
      const int row = 32 * dt + ql;
      const bf16* vbase = &Vs[buf][row * 64];
#pragma unroll
      for (int ks = 0; ks < 4; ++ks) {
        bf16x8 vf = *(const bf16x8*)&vbase[((2 * ks + hi) ^ (row & 7)) * 8];
        oacc[dt] = MFMA32(vf, __builtin_bit_cast(bf16x8, pb[ks]), oacc[dt]);
      }
    }
    __builtin_amdgcn_s_setprio(0);

    w = wnext;
    __builtin_amdgcn_sched_barrier(0);
    __builtin_amdgcn_s_barrier();  // all waves done reading buf -> next stage may overwrite
  }

  const float lsum = lacc[0];  // every reg row holds the same column-sum
  if constexpr (SPLITS == 2) {
    float* opr = opart + ((size_t)(half * 32 + bh) * Sc + qrow) * 64;
#pragma unroll
    for (int dt = 0; dt < 2; ++dt)
#pragma unroll
      for (int i = 0; i < 4; ++i) {
        f32x4 o4;
#pragma unroll
        for (int rr = 0; rr < 4; ++rr) o4[rr] = oacc[dt][4 * i + rr];
        *(f32x4*)&opr[32 * dt + 8 * i + 4 * hi] = o4;
      }
    if (hi == 0) {
      float2 v2; v2.x = 0.f; v2.y = lsum;  // fixed base: m = 0 for both halves
      ml[(size_t)(half * 32 + bh) * Sc + qrow] = v2;
    }
  } else {
    const float rinv = 1.f / fmaxf(lsum, 1e-35f);
    bf16* cp = ctx + (size_t)(b * Sc + qrow) * Dc + h * DKc;
#pragma unroll
    for (int dt = 0; dt < 2; ++dt)
#pragma unroll
      for (int i = 0; i < 4; ++i) {
        bf16x4 o4;
#pragma unroll
        for (int rr = 0; rr < 4; ++rr) o4[rr] = (bf16)(oacc[dt][4 * i + rr] * rinv);
        *(bf16x4*)&cp[32 * dt + 8 * i + 4 * hi] = o4;
      }
  }
}

// ---------------- combine the two KV-splits: exact f32 flash merge ----------------
__global__ __launch_bounds__(256) void combine_kernel(const float* __restrict__ op,
                                                      const float2* __restrict__ ml,
                                                      bf16* __restrict__ ctx) {
  const int wv = threadIdx.x >> 6, lane = threadIdx.x & 63;
  const size_t row = (size_t)blockIdx.x * 4 + wv;      // bh*2048 + q, 0..65535
  const int bh = (int)(row >> 11), q = (int)(row & 2047);
  const int b = bh >> 4, h = bh & 15;
  const float2 ml0 = ml[row], ml1 = ml[65536 + row];
  const float o0 = op[row * 64 + lane];
  const float o1 = op[(size_t)65536 * 64 + row * 64 + lane];
  const float m = fmaxf(ml0.x, ml1.x);
  const float a0 = exp2f(ml0.x - m), a1 = exp2f(ml1.x - m);
  const float l = fmaxf(a0 * ml0.y + a1 * ml1.y, 1e-35f);
  const float o = (a0 * o0 + a1 * o1) / l;
  ctx[((size_t)(b * Sc + q)) * Dc + h * DKc + lane] = (bf16)o;
}

extern "C" void kernel_launch(void* const* d_in, const int* in_sizes, int n_in,
                              void* d_out, int out_size, void* d_ws, size_t ws_size,
                              hipStream_t stream) {
  (void)in_sizes; (void)n_in; (void)out_size;
  const float* q  = (const float*)d_in[0];
  const float* k  = (const float*)d_in[1];
  const float* v  = (const float*)d_in[2];
  const float* Wq = (const float*)d_in[3];
  const float* bq = (const float*)d_in[4];
  const float* Wk = (const float*)d_in[5];
  const float* bk = (const float*)d_in[6];
  const float* Wv = (const float*)d_in[7];
  const float* bv = (const float*)d_in[8];
  const float* Wo = (const float*)d_in[9];
  const float* bo = (const float*)d_in[10];
  const int* mask = (const int*)d_in[11];

  char* ws = (char*)d_ws;
  size_t off = 0;
  auto take = [&](size_t bytes) -> void* {
    void* p = ws + off;
    off += (bytes + 255) & ~(size_t)255;
    return p;
  };
  bf16* qh  = (bf16*)take((size_t)Mc * Dc * 2);
  bf16* kh  = (bf16*)take((size_t)Mc * Dc * 2);
  bf16* vt  = (bf16*)take((size_t)Mc * Dc * 2);
  bf16* ctx = (bf16*)take((size_t)Mc * Dc * 2);
  u64* mbits = (u64*)take((size_t)Bc * Sc * MW * 8);
  bf16* wqb = (bf16*)take((size_t)Dc * Dc * 2);
  bf16* wkb = (bf16*)take((size_t)Dc * Dc * 2);
  bf16* wvb = (bf16*)take((size_t)Dc * Dc * 2);
  bf16* wob = (bf16*)take((size_t)Dc * Dc * 2);
  float* opart = (float*)take((size_t)2 * 32 * Sc * 64 * 4);   // [split][bh][q][64] f32
  float2* mlb = (float2*)take((size_t)2 * 32 * Sc * 8);        // [split][bh][q] (m,l)
  const bool split2 = off <= ws_size;

  convw_kernel<<<dim3(512, 4), 256, 0, stream>>>(Wq, Wk, Wv, Wo, wqb, wkb, wvb, wob);
  packmask_kernel<<<512, 256, 0, stream>>>(mask, mbits, Bc * Sc * Sc / 64);
  gemm_qkv_kernel<<<768, 256, 0, stream>>>(q, k, v, wqb, wkb, wvb, bq, bk, bv, qh, kh, vt);
  if (split2) {
    attn_kernel<2><<<1024, 256, 0, stream>>>(qh, kh, vt, mbits, ctx, opart, mlb);
    combine_kernel<<<16384, 256, 0, stream>>>(opart, mlb, ctx);
  } else {
    attn_kernel<1><<<512, 256, 0, stream>>>(qh, kh, vt, mbits, ctx, opart, mlb);
  }
  gemm_o_kernel<<<512, 256, 0, stream>>>(ctx, wob, bo, (float*)d_out);
}